// Round 1
// baseline (5050.483 us; speedup 1.0000x reference)
//
#include <hip/hip_runtime.h>

// ---------------------------------------------------------------------------
// CSR build kernels
// ---------------------------------------------------------------------------

__global__ __launch_bounds__(256) void hist_k(const int* dst, int E, int* counts) {
    int e = blockIdx.x * 256 + threadIdx.x;
    if (e < E) atomicAdd(&counts[dst[e]], 1);
}

// single-block exclusive scan over counts[0..n) -> row_ptr[0..n], cursor copy.
// counts may alias cursor (each slot read-then-written by the same thread).
__global__ __launch_bounds__(256) void scan_rowptr(const int* counts, int n,
                                                   int* row_ptr, int* cursor) {
    __shared__ int sh[256];
    __shared__ int carry_sh;
    const int tid = threadIdx.x;
    if (tid == 0) carry_sh = 0;
    __syncthreads();
    for (int base = 0; base < n; base += 256) {
        int i = base + tid;
        int v = (i < n) ? counts[i] : 0;
        sh[tid] = v;
        __syncthreads();
        #pragma unroll
        for (int off = 1; off < 256; off <<= 1) {
            int t = (tid >= off) ? sh[tid - off] : 0;
            __syncthreads();
            sh[tid] += t;
            __syncthreads();
        }
        int incl  = sh[tid];
        int total = sh[255];
        int c     = carry_sh;
        __syncthreads();
        int excl = c + incl - v;
        if (i < n) { row_ptr[i] = excl; cursor[i] = excl; }
        if (tid == 0) carry_sh = c + total;
        __syncthreads();
    }
    if (tid == 0) row_ptr[n] = carry_sh;
}

__global__ __launch_bounds__(256) void scatter_k(const int* ei, const float* w, int E,
                                                 int* cursor, int* perm_src, float* perm_w) {
    int e = blockIdx.x * 256 + threadIdx.x;
    if (e < E) {
        int d = ei[e];        // dst = ei[0]
        int s = ei[E + e];    // src = ei[1]
        int pos = atomicAdd(&cursor[d], 1);
        perm_src[pos] = s;
        perm_w[pos]   = w[e];
    }
}

// ---------------------------------------------------------------------------
// SpMM (CSR, gather-only): out[row,:] = sum_e w_e * x[src_e,:]  (+bias, relu)
// one wave per row; F = 64*VEC
// ---------------------------------------------------------------------------

template<int VEC, bool RELU>
__global__ __launch_bounds__(256) void spmm_csr(const float* __restrict__ x,
                                                const int*   __restrict__ perm_src,
                                                const float* __restrict__ perm_w,
                                                const int*   __restrict__ row_ptr,
                                                const float* __restrict__ bias,
                                                float* __restrict__ out, int n) {
    const int wave = threadIdx.x >> 6;
    const int lane = threadIdx.x & 63;
    const int row  = blockIdx.x * 4 + wave;
    if (row >= n) return;
    const int F = 64 * VEC;
    const int e0 = row_ptr[row], e1 = row_ptr[row + 1];
    float acc[VEC];
    #pragma unroll
    for (int v = 0; v < VEC; ++v) acc[v] = 0.f;

    for (int eb = e0; eb < e1; eb += 64) {
        int cnt = min(64, e1 - eb);
        int   myS = 0;
        float myW = 0.f;
        if (eb + lane < e1) { myS = perm_src[eb + lane]; myW = perm_w[eb + lane]; }
        for (int j = 0; j < cnt; ++j) {
            int   s = __shfl(myS, j);
            float w = __shfl(myW, j);
            const float* xr = x + (size_t)s * F + lane * VEC;
            if (VEC == 4) {
                float4 v4 = *reinterpret_cast<const float4*>(xr);
                acc[0] += w * v4.x; acc[1] += w * v4.y;
                acc[2] += w * v4.z; acc[3] += w * v4.w;
            } else {
                float2 v2 = *reinterpret_cast<const float2*>(xr);
                acc[0] += w * v2.x; acc[1] += w * v2.y;
            }
        }
    }

    float o[VEC];
    #pragma unroll
    for (int v = 0; v < VEC; ++v) {
        float val = acc[v] + bias[lane * VEC + v];
        o[v] = RELU ? fmaxf(val, 0.f) : val;
    }
    float* orow = out + (size_t)row * F + lane * VEC;
    if (VEC == 4) *reinterpret_cast<float4*>(orow) = make_float4(o[0], o[1], o[2], o[3]);
    else          *reinterpret_cast<float2*>(orow) = make_float2(o[0], o[1]);
}

// ---------------------------------------------------------------------------
// Tiled f32 GEMM: C[M,N] = A[M,K] @ B[K,N]   (64x64 tile, BK=16, 256 thr, 4x4/thr)
// FUSE: A-operand is concat([A, A2], axis=1), each [M,128], K=256.
// ---------------------------------------------------------------------------

template<bool FUSE, bool RELU, bool BIAS>
__global__ __launch_bounds__(256) void gemm_tile(const float* __restrict__ A,
                                                 const float* __restrict__ A2,
                                                 const float* __restrict__ B,
                                                 const float* __restrict__ bias,
                                                 float* __restrict__ C,
                                                 int M, int N, int K) {
    __shared__ float As[16][68];
    __shared__ float Bs[16][68];
    const int tid = threadIdx.x;
    const int tx = tid & 15, ty = tid >> 4;
    const int bm = blockIdx.x * 64, bn = blockIdx.y * 64;

    float acc[4][4] = {};

    for (int k0 = 0; k0 < K; k0 += 16) {
        #pragma unroll
        for (int i = 0; i < 4; ++i) {
            int e = tid + 256 * i;
            int m = e >> 4, k = e & 15;
            int row = bm + m;
            float v = 0.f;
            if (row < M) {
                int kk = k0 + k;
                if (FUSE) {
                    const float* Ap = (kk < 128) ? A : A2;
                    v = Ap[(size_t)row * 128 + (kk & 127)];
                } else {
                    v = A[(size_t)row * K + kk];
                }
            }
            As[k][m] = v;
        }
        #pragma unroll
        for (int i = 0; i < 4; ++i) {
            int e = tid + 256 * i;
            int k = e >> 6, nn = e & 63;
            Bs[k][nn] = B[(size_t)(k0 + k) * N + bn + nn];
        }
        __syncthreads();
        #pragma unroll
        for (int k = 0; k < 16; ++k) {
            float a[4], b[4];
            #pragma unroll
            for (int i = 0; i < 4; ++i) a[i] = As[k][ty * 4 + i];
            #pragma unroll
            for (int j = 0; j < 4; ++j) b[j] = Bs[k][tx * 4 + j];
            #pragma unroll
            for (int i = 0; i < 4; ++i)
                #pragma unroll
                for (int j = 0; j < 4; ++j)
                    acc[i][j] += a[i] * b[j];
        }
        __syncthreads();
    }

    #pragma unroll
    for (int i = 0; i < 4; ++i) {
        int row = bm + ty * 4 + i;
        if (row >= M) continue;
        #pragma unroll
        for (int j = 0; j < 4; ++j) {
            int col = bn + tx * 4 + j;
            float v = acc[i][j];
            if (BIAS) v += bias[col];
            if (RELU) v = fmaxf(v, 0.f);
            C[(size_t)row * N + col] = v;
        }
    }
}

// ---------------------------------------------------------------------------
// Orchestration
// ---------------------------------------------------------------------------

extern "C" void kernel_launch(void* const* d_in, const int* in_sizes, int n_in,
                              void* d_out, int out_size, void* d_ws, size_t ws_size,
                              hipStream_t stream) {
    const float* Xd       = (const float*)d_in[0];
    const int*   eid_sim  = (const int*)  d_in[1];
    const float* wd_sim   = (const float*)d_in[2];
    const int*   eid_feat = (const int*)  d_in[3];
    const float* wd_feat  = (const float*)d_in[4];
    const float* Xs       = (const float*)d_in[5];
    const int*   eis_sim  = (const int*)  d_in[6];
    const float* ws_sim   = (const float*)d_in[7];
    const int*   eis_feat = (const int*)  d_in[8];
    const float* ws_feat  = (const float*)d_in[9];
    const float* W1d = (const float*)d_in[10]; const float* b1d = (const float*)d_in[11];
    const float* W2d = (const float*)d_in[12]; const float* b2d = (const float*)d_in[13];
    const float* W1s = (const float*)d_in[14]; const float* b1s = (const float*)d_in[15];
    const float* W2s = (const float*)d_in[16]; const float* b2s = (const float*)d_in[17];
    const float* Wfd = (const float*)d_in[18]; const float* bfd = (const float*)d_in[19];
    const float* Wfs = (const float*)d_in[20]; const float* bfs = (const float*)d_in[21];

    const int Fd = 256, H1 = 256, H2 = 128;
    const int Nd = in_sizes[0] / Fd;
    const int Ns = in_sizes[5] / Fd;
    const int Ed = in_sizes[2];
    const int Es = in_sizes[7];

    float* out    = (float*)d_out;
    float* o_emb1 = out;
    float* o_emb2 = o_emb1 + (size_t)Nd * H2;
    float* o_e1s  = o_emb2 + (size_t)Ns * H2;
    float* o_e1f  = o_e1s  + (size_t)Nd * H2;
    float* o_e2s  = o_e1f  + (size_t)Nd * H2;
    float* o_e2f  = o_e2s  + (size_t)Ns * H2;

    char* p = (char*)d_ws;
    float* XW1      = (float*)p; p += (size_t)Nd * H1 * 4;
    float* hbuf     = (float*)p; p += (size_t)Nd * H1 * 4;
    float* tbuf     = (float*)p; p += (size_t)Nd * H2 * 4;
    int*   perm_src = (int*)  p; p += (size_t)Ed * 4;
    float* perm_w   = (float*)p; p += (size_t)Ed * 4;
    int*   row_ptr  = (int*)  p; p += (size_t)(Nd + 1) * 4;
    int*   cursor   = (int*)  p; p += (size_t)Nd * 4;

    auto gemm = [&](const float* A, const float* B, float* C, int M, int N, int K) {
        dim3 g((M + 63) / 64, N / 64);
        gemm_tile<false, false, false><<<g, 256, 0, stream>>>(A, nullptr, B, nullptr, C, M, N, K);
    };

    auto run_branch = [&](const float* X, int n,
                          const int* ei1, const float* w1,
                          const int* ei2, const float* w2, int E,
                          const float* W1, const float* b1,
                          const float* W2, const float* b2,
                          float* out_sim, float* out_feat) {
        gemm(X, W1, XW1, n, H1, Fd);   // x @ W1 shared by both graphs
        const int*   eis[2]  = {ei1, ei2};
        const float* ws[2]   = {w1, w2};
        float*       outs[2] = {out_sim, out_feat};
        for (int g = 0; g < 2; ++g) {
            hipMemsetAsync(cursor, 0, (size_t)n * sizeof(int), stream);
            hist_k<<<(E + 255) / 256, 256, 0, stream>>>(eis[g], E, cursor);
            scan_rowptr<<<1, 256, 0, stream>>>(cursor, n, row_ptr, cursor);
            scatter_k<<<(E + 255) / 256, 256, 0, stream>>>(eis[g], ws[g], E, cursor, perm_src, perm_w);
            // layer 1: h = relu(spmm(XW1) + b1), F=256
            spmm_csr<4, true><<<(n + 3) / 4, 256, 0, stream>>>(XW1, perm_src, perm_w, row_ptr, b1, hbuf, n);
            // h @ W2
            gemm(hbuf, W2, tbuf, n, H2, H1);
            // layer 2: emb = spmm(t) + b2, F=128
            spmm_csr<2, false><<<(n + 3) / 4, 256, 0, stream>>>(tbuf, perm_src, perm_w, row_ptr, b2, outs[g], n);
        }
    };

    run_branch(Xd, Nd, eid_sim, wd_sim, eid_feat, wd_feat, Ed, W1d, b1d, W2d, b2d, o_e1s, o_e1f);
    run_branch(Xs, Ns, eis_sim, ws_sim, eis_feat, ws_feat, Es, W1s, b1s, W2s, b2s, o_e2s, o_e2f);

    // fusion: emb = relu(concat([sim, feat]) @ Wf + bf)
    {
        dim3 g1((Nd + 63) / 64, H2 / 64);
        gemm_tile<true, true, true><<<g1, 256, 0, stream>>>(o_e1s, o_e1f, Wfd, bfd, o_emb1, Nd, H2, 2 * H2);
        dim3 g2((Ns + 63) / 64, H2 / 64);
        gemm_tile<true, true, true><<<g2, 256, 0, stream>>>(o_e2s, o_e2f, Wfs, bfs, o_emb2, Ns, H2, 2 * H2);
    }
}

// Round 2
// 2234.818 us; speedup vs baseline: 2.2599x; 2.2599x over previous
//
#include <hip/hip_runtime.h>

typedef __attribute__((ext_vector_type(8))) short bf16x8;
typedef __attribute__((ext_vector_type(4))) float f32x4;

__device__ inline ushort f2bf(float f) {
    uint u = __float_as_uint(f);
    u += 0x7fff + ((u >> 16) & 1);
    return (ushort)(u >> 16);
}
__device__ inline float bflo(uint u) { return __uint_as_float(u << 16); }
__device__ inline float bfhi(uint u) { return __uint_as_float(u & 0xffff0000u); }

// ---------------------------------------------------------------------------
// f32 -> bf16 vectorized convert
// ---------------------------------------------------------------------------
__global__ __launch_bounds__(256) void f2bf_vec(const float* __restrict__ in,
                                                ushort* __restrict__ out, int n4) {
    for (int i = blockIdx.x * 256 + threadIdx.x; i < n4; i += gridDim.x * 256) {
        float4 v = reinterpret_cast<const float4*>(in)[i];
        reinterpret_cast<ushort4*>(out)[i] =
            make_ushort4(f2bf(v.x), f2bf(v.y), f2bf(v.z), f2bf(v.w));
    }
}

// transpose + convert: W[K,N] f32 -> Wt[N,K] bf16. K,N multiples of 32.
__global__ __launch_bounds__(256) void transpose_bf16_k(const float* __restrict__ W,
                                                        ushort* __restrict__ Wt,
                                                        int K, int N) {
    __shared__ ushort tile[32][33];
    int k0 = blockIdx.x * 32, n0 = blockIdx.y * 32;
    int tx = threadIdx.x & 31, ty = threadIdx.x >> 5;
    #pragma unroll
    for (int i = 0; i < 32; i += 8)
        tile[ty + i][tx] = f2bf(W[(size_t)(k0 + ty + i) * N + n0 + tx]);
    __syncthreads();
    #pragma unroll
    for (int i = 0; i < 32; i += 8)
        Wt[(size_t)(n0 + ty + i) * K + k0 + tx] = tile[tx][ty + i];
}

// ---------------------------------------------------------------------------
// CSR build
// ---------------------------------------------------------------------------
__global__ __launch_bounds__(256) void hist_k(const int* dst, int E, int* counts) {
    int e = blockIdx.x * 256 + threadIdx.x;
    if (e < E) atomicAdd(&counts[dst[e]], 1);
}

__global__ __launch_bounds__(256) void scan_p1(const int* __restrict__ counts, int n,
                                               int* __restrict__ bsums) {
    int b = blockIdx.x, t = threadIdx.x;
    int base = b * 1024 + t * 4;
    int s = 0;
    if (base + 4 <= n) {
        int4 v = *reinterpret_cast<const int4*>(counts + base);
        s = v.x + v.y + v.z + v.w;
    } else {
        for (int i = 0; i < 4; ++i) if (base + i < n) s += counts[base + i];
    }
    for (int off = 32; off >= 1; off >>= 1) s += __shfl_down(s, off);
    __shared__ int red[4];
    if ((t & 63) == 0) red[t >> 6] = s;
    __syncthreads();
    if (t == 0) bsums[b] = red[0] + red[1] + red[2] + red[3];
}

__global__ __launch_bounds__(256) void scan_p2(int* bsums, int B) {
    int t = threadIdx.x;
    int v = (t < B) ? bsums[t] : 0;
    int lane = t & 63, wave = t >> 6;
    int s = v;
    for (int off = 1; off < 64; off <<= 1) {
        int u = __shfl_up(s, off);
        if (lane >= off) s += u;
    }
    __shared__ int wsum[4];
    if (lane == 63) wsum[wave] = s;
    __syncthreads();
    int woff = 0;
    for (int wv = 0; wv < 4; ++wv) if (wv < wave) woff += wsum[wv];
    if (t < B) bsums[t] = s + woff - v;   // exclusive
}

__global__ __launch_bounds__(256) void scan_p3(const int* __restrict__ counts, int n, int E,
                                               const int* __restrict__ bsums,
                                               int* __restrict__ row_ptr,
                                               int* __restrict__ cursor) {
    int b = blockIdx.x, t = threadIdx.x;
    int base = b * 1024 + t * 4;
    int c[4];
    if (base + 4 <= n) {
        int4 v = *reinterpret_cast<const int4*>(counts + base);
        c[0] = v.x; c[1] = v.y; c[2] = v.z; c[3] = v.w;
    } else {
        for (int i = 0; i < 4; ++i) c[i] = (base + i < n) ? counts[base + i] : 0;
    }
    int s = c[0] + c[1] + c[2] + c[3];
    int lane = t & 63, wave = t >> 6;
    int incl = s;
    for (int off = 1; off < 64; off <<= 1) {
        int u = __shfl_up(incl, off);
        if (lane >= off) incl += u;
    }
    __shared__ int wsum[4];
    if (lane == 63) wsum[wave] = incl;
    __syncthreads();
    int excl = bsums[b] + incl - s;
    for (int wv = 0; wv < wave; ++wv) excl += wsum[wv];
    for (int i = 0; i < 4; ++i) {
        if (base + i < n) { row_ptr[base + i] = excl; cursor[base + i] = excl; }
        excl += c[i];
    }
    if (b == 0 && t == 0) row_ptr[n] = E;
}

__global__ __launch_bounds__(256) void scatter_k(const int* ei, const float* w, int E,
                                                 int* cursor, int* perm_src, float* perm_w) {
    int e = blockIdx.x * 256 + threadIdx.x;
    if (e < E) {
        int d = ei[e];
        int s = ei[E + e];
        int pos = atomicAdd(&cursor[d], 1);
        perm_src[pos] = s;
        perm_w[pos]   = w[e];
    }
}

// ---------------------------------------------------------------------------
// SpMM over bf16 table: out[row,:] = sum_e w_e * x[src_e,:] (+bias)(relu)
// one wave per row, F = 64*C. Writes bf16 always; DUAL adds f32 output.
// ---------------------------------------------------------------------------
template<int C, bool RELU, bool DUAL>
__global__ __launch_bounds__(256) void spmm_bf16(
    const ushort* __restrict__ x,
    const int* __restrict__ perm_src, const float* __restrict__ perm_w,
    const int* __restrict__ row_ptr, const float* __restrict__ bias,
    ushort* __restrict__ out_bf, float* __restrict__ out_f32, int n)
{
    __shared__ int2 sE[4][64];
    const int wave = threadIdx.x >> 6, lane = threadIdx.x & 63;
    const int row = blockIdx.x * 4 + wave;
    if (row >= n) return;
    const int F = 64 * C;
    const int e0 = row_ptr[row], e1 = row_ptr[row + 1];
    float acc[C] = {};
    const ushort* xb = x + (size_t)lane * C;

    for (int eb = e0; eb < e1; eb += 64) {
        int m = min(64, e1 - eb);
        if (eb + lane < e1)
            sE[wave][lane] = make_int2(perm_src[eb + lane], __float_as_int(perm_w[eb + lane]));
        int j = 0;
        for (; j + 4 <= m; j += 4) {
            int2 a0 = sE[wave][j], a1 = sE[wave][j+1], a2 = sE[wave][j+2], a3 = sE[wave][j+3];
            float w0 = __int_as_float(a0.y), w1 = __int_as_float(a1.y);
            float w2 = __int_as_float(a2.y), w3 = __int_as_float(a3.y);
            if (C == 4) {
                uint2 v0 = *reinterpret_cast<const uint2*>(xb + (size_t)a0.x * F);
                uint2 v1 = *reinterpret_cast<const uint2*>(xb + (size_t)a1.x * F);
                uint2 v2 = *reinterpret_cast<const uint2*>(xb + (size_t)a2.x * F);
                uint2 v3 = *reinterpret_cast<const uint2*>(xb + (size_t)a3.x * F);
                acc[0] += w0*bflo(v0.x); acc[1] += w0*bfhi(v0.x); acc[2] += w0*bflo(v0.y); acc[3] += w0*bfhi(v0.y);
                acc[0] += w1*bflo(v1.x); acc[1] += w1*bfhi(v1.x); acc[2] += w1*bflo(v1.y); acc[3] += w1*bfhi(v1.y);
                acc[0] += w2*bflo(v2.x); acc[1] += w2*bfhi(v2.x); acc[2] += w2*bflo(v2.y); acc[3] += w2*bfhi(v2.y);
                acc[0] += w3*bflo(v3.x); acc[1] += w3*bfhi(v3.x); acc[2] += w3*bflo(v3.y); acc[3] += w3*bfhi(v3.y);
            } else {
                uint v0 = *reinterpret_cast<const uint*>(xb + (size_t)a0.x * F);
                uint v1 = *reinterpret_cast<const uint*>(xb + (size_t)a1.x * F);
                uint v2 = *reinterpret_cast<const uint*>(xb + (size_t)a2.x * F);
                uint v3 = *reinterpret_cast<const uint*>(xb + (size_t)a3.x * F);
                acc[0] += w0*bflo(v0); acc[1] += w0*bfhi(v0);
                acc[0] += w1*bflo(v1); acc[1] += w1*bfhi(v1);
                acc[0] += w2*bflo(v2); acc[1] += w2*bfhi(v2);
                acc[0] += w3*bflo(v3); acc[1] += w3*bfhi(v3);
            }
        }
        for (; j < m; ++j) {
            int2 a = sE[wave][j];
            float w = __int_as_float(a.y);
            if (C == 4) {
                uint2 v = *reinterpret_cast<const uint2*>(xb + (size_t)a.x * F);
                acc[0] += w*bflo(v.x); acc[1] += w*bfhi(v.x); acc[2] += w*bflo(v.y); acc[3] += w*bfhi(v.y);
            } else {
                uint v = *reinterpret_cast<const uint*>(xb + (size_t)a.x * F);
                acc[0] += w*bflo(v); acc[1] += w*bfhi(v);
            }
        }
    }

    #pragma unroll
    for (int c = 0; c < C; ++c) {
        float v = acc[c] + bias[lane * C + c];
        acc[c] = RELU ? fmaxf(v, 0.f) : v;
    }
    size_t ob = (size_t)row * F + lane * C;
    if (DUAL) {
        if (C == 4) *reinterpret_cast<float4*>(out_f32 + ob) = make_float4(acc[0], acc[1], acc[2], acc[3]);
        else        *reinterpret_cast<float2*>(out_f32 + ob) = make_float2(acc[0], acc[1]);
    }
    if (C == 4) *reinterpret_cast<ushort4*>(out_bf + ob) = make_ushort4(f2bf(acc[0]), f2bf(acc[1]), f2bf(acc[2]), f2bf(acc[3]));
    else        *reinterpret_cast<ushort2*>(out_bf + ob) = make_ushort2(f2bf(acc[0]), f2bf(acc[1]));
}

// ---------------------------------------------------------------------------
// bf16 MFMA GEMM: C[M,N] = A[M,K] @ Bt[N,K]^T, 128x128 tile, BK=32, 4 waves.
// FUSE: A-operand is concat([A,A2],axis=1), each [M,128], K=256.
// XOR-swizzled LDS (cb' = cb ^ ((r>>1)&3)) -> 2-way-max bank access on b128.
// ---------------------------------------------------------------------------
template<bool FUSE, bool RELU, bool BIAS, bool F32OUT>
__global__ __launch_bounds__(256) void gemm_mfma(
    const ushort* __restrict__ A, const ushort* __restrict__ A2,
    const ushort* __restrict__ Bt, const float* __restrict__ bias,
    ushort* __restrict__ Cbf, float* __restrict__ Cf,
    int M, int N, int K)
{
    __shared__ ushort Asb[128 * 32];
    __shared__ ushort Bsb[128 * 32];
    const int tid = threadIdx.x;
    const int lane = tid & 63, wave = tid >> 6;
    const int wr = wave >> 1, wc = wave & 1;
    const int bm = blockIdx.x * 128, bn = blockIdx.y * 128;

    f32x4 acc[4][4] = {};

    for (int k0 = 0; k0 < K; k0 += 32) {
        #pragma unroll
        for (int h = 0; h < 2; ++h) {
            int slot = tid + 256 * h;
            int r = slot >> 2, cb = slot & 3;
            int row = bm + r;
            uint4 v = make_uint4(0, 0, 0, 0);
            if (row < M) {
                int kk = k0 + cb * 8;
                if (FUSE) {
                    const ushort* Ap = (kk < 128) ? A : A2;
                    v = *reinterpret_cast<const uint4*>(Ap + (size_t)row * 128 + (kk & 127));
                } else {
                    v = *reinterpret_cast<const uint4*>(A + (size_t)row * K + kk);
                }
            }
            int scb = cb ^ ((r >> 1) & 3);
            *reinterpret_cast<uint4*>(&Asb[r * 32 + scb * 8]) = v;
        }
        #pragma unroll
        for (int h = 0; h < 2; ++h) {
            int slot = tid + 256 * h;
            int r = slot >> 2, cb = slot & 3;
            uint4 v = *reinterpret_cast<const uint4*>(Bt + (size_t)(bn + r) * K + k0 + cb * 8);
            int scb = cb ^ ((r >> 1) & 3);
            *reinterpret_cast<uint4*>(&Bsb[r * 32 + scb * 8]) = v;
        }
        __syncthreads();

        bf16x8 fa[4], fb[4];
        #pragma unroll
        for (int i = 0; i < 4; ++i) {
            int r = wr * 64 + i * 16 + (lane & 15);
            int scb = (lane >> 4) ^ ((r >> 1) & 3);
            fa[i] = *reinterpret_cast<const bf16x8*>(&Asb[r * 32 + scb * 8]);
        }
        #pragma unroll
        for (int j = 0; j < 4; ++j) {
            int r = wc * 64 + j * 16 + (lane & 15);
            int scb = (lane >> 4) ^ ((r >> 1) & 3);
            fb[j] = *reinterpret_cast<const bf16x8*>(&Bsb[r * 32 + scb * 8]);
        }
        #pragma unroll
        for (int i = 0; i < 4; ++i)
            #pragma unroll
            for (int j = 0; j < 4; ++j)
                acc[i][j] = __builtin_amdgcn_mfma_f32_16x16x32_bf16(fa[i], fb[j], acc[i][j], 0, 0, 0);
        __syncthreads();
    }

    // C/D: col = lane&15, row = (lane>>4)*4 + reg
    #pragma unroll
    for (int i = 0; i < 4; ++i) {
        #pragma unroll
        for (int r4 = 0; r4 < 4; ++r4) {
            int row = bm + wr * 64 + i * 16 + (lane >> 4) * 4 + r4;
            if (row >= M) continue;
            #pragma unroll
            for (int j = 0; j < 4; ++j) {
                int col = bn + wc * 64 + j * 16 + (lane & 15);
                float v = acc[i][j][r4];
                if (BIAS) v += bias[col];
                if (RELU) v = fmaxf(v, 0.f);
                if (F32OUT) Cf[(size_t)row * N + col] = v;
                else        Cbf[(size_t)row * N + col] = f2bf(v);
            }
        }
    }
}

// ---------------------------------------------------------------------------
// Orchestration
// ---------------------------------------------------------------------------
extern "C" void kernel_launch(void* const* d_in, const int* in_sizes, int n_in,
                              void* d_out, int out_size, void* d_ws, size_t ws_size,
                              hipStream_t stream) {
    const float* Xd       = (const float*)d_in[0];
    const int*   eid_sim  = (const int*)  d_in[1];
    const float* wd_sim   = (const float*)d_in[2];
    const int*   eid_feat = (const int*)  d_in[3];
    const float* wd_feat  = (const float*)d_in[4];
    const float* Xs       = (const float*)d_in[5];
    const int*   eis_sim  = (const int*)  d_in[6];
    const float* ws_sim   = (const float*)d_in[7];
    const int*   eis_feat = (const int*)  d_in[8];
    const float* ws_feat  = (const float*)d_in[9];
    const float* W1d = (const float*)d_in[10]; const float* b1d = (const float*)d_in[11];
    const float* W2d = (const float*)d_in[12]; const float* b2d = (const float*)d_in[13];
    const float* W1s = (const float*)d_in[14]; const float* b1s = (const float*)d_in[15];
    const float* W2s = (const float*)d_in[16]; const float* b2s = (const float*)d_in[17];
    const float* Wfd = (const float*)d_in[18]; const float* bfd = (const float*)d_in[19];
    const float* Wfs = (const float*)d_in[20]; const float* bfs = (const float*)d_in[21];

    const int Fd = 256, H1 = 256, H2 = 128;
    const int Nd = in_sizes[0] / Fd;
    const int Ns = in_sizes[5] / Fd;
    const int Ed = in_sizes[2];
    const int Es = in_sizes[7];

    float* out    = (float*)d_out;
    float* o_emb1 = out;
    float* o_emb2 = o_emb1 + (size_t)Nd * H2;
    float* o_e1s  = o_emb2 + (size_t)Ns * H2;
    float* o_e1f  = o_e1s  + (size_t)Nd * H2;
    float* o_e2s  = o_e1f  + (size_t)Nd * H2;
    float* o_e2f  = o_e2s  + (size_t)Ns * H2;

    char* p = (char*)d_ws;
    auto alloc = [&](size_t bytes) { char* q = p; p += (bytes + 255) & ~(size_t)255; return q; };
    ushort* x_bf  = (ushort*)alloc((size_t)Nd * 256 * 2);
    ushort* xw1   = (ushort*)alloc((size_t)Nd * 256 * 2);
    ushort* hbf   = (ushort*)alloc((size_t)Nd * 256 * 2);
    ushort* tbf   = (ushort*)alloc((size_t)Nd * 128 * 2);
    ushort* es_bf = (ushort*)alloc((size_t)Nd * 128 * 2);
    ushort* ef_bf = (ushort*)alloc((size_t)Nd * 128 * 2);
    ushort* W1dt  = (ushort*)alloc(256 * 256 * 2);
    ushort* W2dt  = (ushort*)alloc(256 * 128 * 2);
    ushort* Wfdt  = (ushort*)alloc(256 * 128 * 2);
    ushort* W1st  = (ushort*)alloc(256 * 256 * 2);
    ushort* W2st  = (ushort*)alloc(256 * 128 * 2);
    ushort* Wfst  = (ushort*)alloc(256 * 128 * 2);
    int*    perm_src = (int*)  alloc((size_t)Ed * 4);
    float*  perm_w   = (float*)alloc((size_t)Ed * 4);
    int*    row_ptr  = (int*)  alloc((size_t)(Nd + 1) * 4);
    int*    cursor   = (int*)  alloc((size_t)Nd * 4);
    int*    bsums    = (int*)  alloc(256 * 4);

    // weight transposes (f32 -> bf16 [N,K])
    transpose_bf16_k<<<dim3(8, 8), 256, 0, stream>>>(W1d, W1dt, 256, 256);
    transpose_bf16_k<<<dim3(8, 4), 256, 0, stream>>>(W2d, W2dt, 256, 128);
    transpose_bf16_k<<<dim3(8, 4), 256, 0, stream>>>(Wfd, Wfdt, 256, 128);
    transpose_bf16_k<<<dim3(8, 8), 256, 0, stream>>>(W1s, W1st, 256, 256);
    transpose_bf16_k<<<dim3(8, 4), 256, 0, stream>>>(W2s, W2st, 256, 128);
    transpose_bf16_k<<<dim3(8, 4), 256, 0, stream>>>(Wfs, Wfst, 256, 128);

    auto branch = [&](const float* X, int n,
                      const int* ei1, const float* w1,
                      const int* ei2, const float* w2, int E,
                      const ushort* W1t, const float* b1,
                      const ushort* W2t, const float* b2,
                      const ushort* Wft, const float* bfu,
                      float* o_sim, float* o_feat, float* o_emb) {
        f2bf_vec<<<2048, 256, 0, stream>>>(X, x_bf, n * 64);
        gemm_mfma<false, false, false, false><<<dim3((n + 127) / 128, 2), 256, 0, stream>>>(
            x_bf, nullptr, W1t, nullptr, xw1, nullptr, n, 256, 256);
        const int*   eis[2]  = {ei1, ei2};
        const float* wss[2]  = {w1, w2};
        float*       of[2]   = {o_sim, o_feat};
        ushort*      ob[2]   = {es_bf, ef_bf};
        int B = (n + 1023) / 1024;
        for (int g = 0; g < 2; ++g) {
            hipMemsetAsync(cursor, 0, (size_t)n * 4, stream);
            hist_k<<<(E + 255) / 256, 256, 0, stream>>>(eis[g], E, cursor);
            scan_p1<<<B, 256, 0, stream>>>(cursor, n, bsums);
            scan_p2<<<1, 256, 0, stream>>>(bsums, B);
            scan_p3<<<B, 256, 0, stream>>>(cursor, n, E, bsums, row_ptr, cursor);
            scatter_k<<<(E + 255) / 256, 256, 0, stream>>>(eis[g], wss[g], E, cursor, perm_src, perm_w);
            spmm_bf16<4, true, false><<<(n + 3) / 4, 256, 0, stream>>>(
                xw1, perm_src, perm_w, row_ptr, b1, hbf, nullptr, n);
            gemm_mfma<false, false, false, false><<<dim3((n + 127) / 128, 1), 256, 0, stream>>>(
                hbf, nullptr, W2t, nullptr, tbf, nullptr, n, 128, 256);
            spmm_bf16<2, false, true><<<(n + 3) / 4, 256, 0, stream>>>(
                tbf, perm_src, perm_w, row_ptr, b2, ob[g], of[g], n);
        }
        gemm_mfma<true, true, true, true><<<dim3((n + 127) / 128, 1), 256, 0, stream>>>(
            es_bf, ef_bf, Wft, bfu, nullptr, o_emb, n, 128, 256);
    };

    branch(Xd, Nd, eid_sim, wd_sim, eid_feat, wd_feat, Ed,
           W1dt, b1d, W2dt, b2d, Wfdt, bfd, o_e1s, o_e1f, o_emb1);
    branch(Xs, Ns, eis_sim, ws_sim, eis_feat, ws_feat, Es,
           W1st, b1s, W2st, b2s, Wfst, bfs, o_e2s, o_e2f, o_emb2);
}

// Round 3
// 2228.901 us; speedup vs baseline: 2.2659x; 1.0027x over previous
//
#include <hip/hip_runtime.h>

typedef _Float16 f16;
typedef __attribute__((ext_vector_type(8))) _Float16 f16x8;
typedef __attribute__((ext_vector_type(4))) float f32x4;

__device__ inline ushort f2h_bits(float f) {
    f16 h = (f16)f;
    return __builtin_bit_cast(ushort, h);
}

// ---------------------------------------------------------------------------
// f32 -> f16 vectorized convert
// ---------------------------------------------------------------------------
__global__ __launch_bounds__(256) void f2h_vec(const float* __restrict__ in,
                                               ushort* __restrict__ out, int n4) {
    for (int i = blockIdx.x * 256 + threadIdx.x; i < n4; i += gridDim.x * 256) {
        float4 v = reinterpret_cast<const float4*>(in)[i];
        reinterpret_cast<ushort4*>(out)[i] =
            make_ushort4(f2h_bits(v.x), f2h_bits(v.y), f2h_bits(v.z), f2h_bits(v.w));
    }
}

// transpose + convert: W[K,N] f32 -> Wt[N,K] f16. K,N multiples of 32.
__global__ __launch_bounds__(256) void transpose_f16_k(const float* __restrict__ W,
                                                       ushort* __restrict__ Wt,
                                                       int K, int N) {
    __shared__ ushort tile[32][33];
    int k0 = blockIdx.x * 32, n0 = blockIdx.y * 32;
    int tx = threadIdx.x & 31, ty = threadIdx.x >> 5;
    #pragma unroll
    for (int i = 0; i < 32; i += 8)
        tile[ty + i][tx] = f2h_bits(W[(size_t)(k0 + ty + i) * N + n0 + tx]);
    __syncthreads();
    #pragma unroll
    for (int i = 0; i < 32; i += 8)
        Wt[(size_t)(n0 + ty + i) * K + k0 + tx] = tile[tx][ty + i];
}

// ---------------------------------------------------------------------------
// CSR build
// ---------------------------------------------------------------------------
__global__ __launch_bounds__(256) void hist_k(const int* dst, int E, int* counts) {
    int e = blockIdx.x * 256 + threadIdx.x;
    if (e < E) atomicAdd(&counts[dst[e]], 1);
}

__global__ __launch_bounds__(256) void scan_p1(const int* __restrict__ counts, int n,
                                               int* __restrict__ bsums) {
    int b = blockIdx.x, t = threadIdx.x;
    int base = b * 1024 + t * 4;
    int s = 0;
    if (base + 4 <= n) {
        int4 v = *reinterpret_cast<const int4*>(counts + base);
        s = v.x + v.y + v.z + v.w;
    } else {
        for (int i = 0; i < 4; ++i) if (base + i < n) s += counts[base + i];
    }
    for (int off = 32; off >= 1; off >>= 1) s += __shfl_down(s, off);
    __shared__ int red[4];
    if ((t & 63) == 0) red[t >> 6] = s;
    __syncthreads();
    if (t == 0) bsums[b] = red[0] + red[1] + red[2] + red[3];
}

__global__ __launch_bounds__(256) void scan_p2(int* bsums, int B) {
    int t = threadIdx.x;
    int v = (t < B) ? bsums[t] : 0;
    int lane = t & 63, wave = t >> 6;
    int s = v;
    for (int off = 1; off < 64; off <<= 1) {
        int u = __shfl_up(s, off);
        if (lane >= off) s += u;
    }
    __shared__ int wsum[4];
    if (lane == 63) wsum[wave] = s;
    __syncthreads();
    int woff = 0;
    for (int wv = 0; wv < 4; ++wv) if (wv < wave) woff += wsum[wv];
    if (t < B) bsums[t] = s + woff - v;   // exclusive
}

__global__ __launch_bounds__(256) void scan_p3(const int* __restrict__ counts, int n, int E,
                                               const int* __restrict__ bsums,
                                               int* __restrict__ row_ptr,
                                               int* __restrict__ cursor) {
    int b = blockIdx.x, t = threadIdx.x;
    int base = b * 1024 + t * 4;
    int c[4];
    if (base + 4 <= n) {
        int4 v = *reinterpret_cast<const int4*>(counts + base);
        c[0] = v.x; c[1] = v.y; c[2] = v.z; c[3] = v.w;
    } else {
        for (int i = 0; i < 4; ++i) c[i] = (base + i < n) ? counts[base + i] : 0;
    }
    int s = c[0] + c[1] + c[2] + c[3];
    int lane = t & 63, wave = t >> 6;
    int incl = s;
    for (int off = 1; off < 64; off <<= 1) {
        int u = __shfl_up(incl, off);
        if (lane >= off) incl += u;
    }
    __shared__ int wsum[4];
    if (lane == 63) wsum[wave] = incl;
    __syncthreads();
    int excl = bsums[b] + incl - s;
    for (int wv = 0; wv < wave; ++wv) excl += wsum[wv];
    for (int i = 0; i < 4; ++i) {
        if (base + i < n) { row_ptr[base + i] = excl; cursor[base + i] = excl; }
        excl += c[i];
    }
    if (b == 0 && t == 0) row_ptr[n] = E;
}

__global__ __launch_bounds__(256) void scatter_k(const int* ei, const float* w, int E,
                                                 int* cursor, int* perm_src, float* perm_w) {
    int e = blockIdx.x * 256 + threadIdx.x;
    if (e < E) {
        int d = ei[e];
        int s = ei[E + e];
        int pos = atomicAdd(&cursor[d], 1);
        perm_src[pos] = s;
        perm_w[pos]   = w[e];
    }
}

// ---------------------------------------------------------------------------
// SpMM over f16 table: out[row,:] = sum_e w_e * x[src_e,:] (+bias)(relu)
// one wave per row, F = 64*C. Edge records held in lane regs, broadcast via
// readlane -> SGPR (src row base becomes SALU math). 8 loads in flight.
// ---------------------------------------------------------------------------
template<int C, bool RELU, bool DUAL>
__global__ __launch_bounds__(256) void spmm_f16(
    const f16* __restrict__ x,
    const int* __restrict__ perm_src, const float* __restrict__ perm_w,
    const int* __restrict__ row_ptr, const float* __restrict__ bias,
    ushort* __restrict__ out_h, float* __restrict__ out_f, int n)
{
    const int wave = threadIdx.x >> 6, lane = threadIdx.x & 63;
    const int row = blockIdx.x * 4 + wave;
    if (row >= n) return;
    const int F = 64 * C;
    const int e0 = row_ptr[row], e1 = row_ptr[row + 1];
    float acc[C] = {};
    const int laneoff = lane * C;

    for (int eb = e0; eb < e1; eb += 64) {
        int idx = eb + lane;
        int myS = 0; float myW = 0.f;
        if (idx < e1) { myS = perm_src[idx]; myW = perm_w[idx]; }
        int m = min(64, e1 - eb);
        for (int j0 = 0; j0 < m; j0 += 8) {
            #pragma unroll
            for (int u = 0; u < 8; ++u) {
                int j = j0 + u;   // j <= 8*ceil(m/8)-1 <= 63; padded lanes have w=0
                int   s = __builtin_amdgcn_readlane(myS, j);
                float w = __int_as_float(__builtin_amdgcn_readlane(__float_as_int(myW), j));
                const f16* xr = x + (size_t)((uint)s * (uint)F) + laneoff;
                if (C == 4) {
                    union { uint2 u2; f16 h[4]; } cv;
                    cv.u2 = *reinterpret_cast<const uint2*>(xr);
                    acc[0] = fmaf((float)cv.h[0], w, acc[0]);
                    acc[1] = fmaf((float)cv.h[1], w, acc[1]);
                    acc[2] = fmaf((float)cv.h[2], w, acc[2]);
                    acc[3] = fmaf((float)cv.h[3], w, acc[3]);
                } else {
                    union { uint u1; f16 h[2]; } cv;
                    cv.u1 = *reinterpret_cast<const uint*>(xr);
                    acc[0] = fmaf((float)cv.h[0], w, acc[0]);
                    acc[1] = fmaf((float)cv.h[1], w, acc[1]);
                }
            }
        }
    }

    #pragma unroll
    for (int c = 0; c < C; ++c) {
        float v = acc[c] + bias[laneoff + c];
        acc[c] = RELU ? fmaxf(v, 0.f) : v;
    }
    size_t ob = (size_t)row * F + laneoff;
    if (DUAL) {
        if (C == 4) *reinterpret_cast<float4*>(out_f + ob) = make_float4(acc[0], acc[1], acc[2], acc[3]);
        else        *reinterpret_cast<float2*>(out_f + ob) = make_float2(acc[0], acc[1]);
    }
    if (C == 4) *reinterpret_cast<ushort4*>(out_h + ob) =
        make_ushort4(f2h_bits(acc[0]), f2h_bits(acc[1]), f2h_bits(acc[2]), f2h_bits(acc[3]));
    else        *reinterpret_cast<ushort2*>(out_h + ob) =
        make_ushort2(f2h_bits(acc[0]), f2h_bits(acc[1]));
}

// ---------------------------------------------------------------------------
// f16 MFMA GEMM: C[M,N] = A[M,K] @ Bt[N,K]^T, 128x128 tile, BK=32, 4 waves.
// FUSE: A-operand is concat([A,A2],axis=1), each [M,128], K=256.
// XOR-swizzled LDS (cb' = cb ^ ((r>>1)&3)).
// ---------------------------------------------------------------------------
template<bool FUSE, bool RELU, bool BIAS, bool F32OUT>
__global__ __launch_bounds__(256) void gemm_mfma(
    const ushort* __restrict__ A, const ushort* __restrict__ A2,
    const ushort* __restrict__ Bt, const float* __restrict__ bias,
    ushort* __restrict__ Ch, float* __restrict__ Cf,
    int M, int N, int K)
{
    __shared__ ushort Asb[128 * 32];
    __shared__ ushort Bsb[128 * 32];
    const int tid = threadIdx.x;
    const int lane = tid & 63, wave = tid >> 6;
    const int wr = wave >> 1, wc = wave & 1;
    const int bm = blockIdx.x * 128, bn = blockIdx.y * 128;

    f32x4 acc[4][4] = {};

    for (int k0 = 0; k0 < K; k0 += 32) {
        #pragma unroll
        for (int h = 0; h < 2; ++h) {
            int slot = tid + 256 * h;
            int r = slot >> 2, cb = slot & 3;
            int row = bm + r;
            uint4 v = make_uint4(0, 0, 0, 0);
            if (row < M) {
                int kk = k0 + cb * 8;
                if (FUSE) {
                    const ushort* Ap = (kk < 128) ? A : A2;
                    v = *reinterpret_cast<const uint4*>(Ap + (size_t)row * 128 + (kk & 127));
                } else {
                    v = *reinterpret_cast<const uint4*>(A + (size_t)row * K + kk);
                }
            }
            int scb = cb ^ ((r >> 1) & 3);
            *reinterpret_cast<uint4*>(&Asb[r * 32 + scb * 8]) = v;
        }
        #pragma unroll
        for (int h = 0; h < 2; ++h) {
            int slot = tid + 256 * h;
            int r = slot >> 2, cb = slot & 3;
            uint4 v = *reinterpret_cast<const uint4*>(Bt + (size_t)(bn + r) * K + k0 + cb * 8);
            int scb = cb ^ ((r >> 1) & 3);
            *reinterpret_cast<uint4*>(&Bsb[r * 32 + scb * 8]) = v;
        }
        __syncthreads();

        f16x8 fa[4], fb[4];
        #pragma unroll
        for (int i = 0; i < 4; ++i) {
            int r = wr * 64 + i * 16 + (lane & 15);
            int scb = (lane >> 4) ^ ((r >> 1) & 3);
            fa[i] = *reinterpret_cast<const f16x8*>(&Asb[r * 32 + scb * 8]);
        }
        #pragma unroll
        for (int j = 0; j < 4; ++j) {
            int r = wc * 64 + j * 16 + (lane & 15);
            int scb = (lane >> 4) ^ ((r >> 1) & 3);
            fb[j] = *reinterpret_cast<const f16x8*>(&Bsb[r * 32 + scb * 8]);
        }
        #pragma unroll
        for (int i = 0; i < 4; ++i)
            #pragma unroll
            for (int j = 0; j < 4; ++j)
                acc[i][j] = __builtin_amdgcn_mfma_f32_16x16x32_f16(fa[i], fb[j], acc[i][j], 0, 0, 0);
        __syncthreads();
    }

    // C/D: col = lane&15, row = (lane>>4)*4 + reg
    #pragma unroll
    for (int i = 0; i < 4; ++i) {
        #pragma unroll
        for (int r4 = 0; r4 < 4; ++r4) {
            int row = bm + wr * 64 + i * 16 + (lane >> 4) * 4 + r4;
            if (row >= M) continue;
            #pragma unroll
            for (int j = 0; j < 4; ++j) {
                int col = bn + wc * 64 + j * 16 + (lane & 15);
                float v = acc[i][j][r4];
                if (BIAS) v += bias[col];
                if (RELU) v = fmaxf(v, 0.f);
                if (F32OUT) Cf[(size_t)row * N + col] = v;
                else        Ch[(size_t)row * N + col] = f2h_bits(v);
            }
        }
    }
}

// ---------------------------------------------------------------------------
// Orchestration
// ---------------------------------------------------------------------------
extern "C" void kernel_launch(void* const* d_in, const int* in_sizes, int n_in,
                              void* d_out, int out_size, void* d_ws, size_t ws_size,
                              hipStream_t stream) {
    const float* Xd       = (const float*)d_in[0];
    const int*   eid_sim  = (const int*)  d_in[1];
    const float* wd_sim   = (const float*)d_in[2];
    const int*   eid_feat = (const int*)  d_in[3];
    const float* wd_feat  = (const float*)d_in[4];
    const float* Xs       = (const float*)d_in[5];
    const int*   eis_sim  = (const int*)  d_in[6];
    const float* ws_sim   = (const float*)d_in[7];
    const int*   eis_feat = (const int*)  d_in[8];
    const float* ws_feat  = (const float*)d_in[9];
    const float* W1d = (const float*)d_in[10]; const float* b1d = (const float*)d_in[11];
    const float* W2d = (const float*)d_in[12]; const float* b2d = (const float*)d_in[13];
    const float* W1s = (const float*)d_in[14]; const float* b1s = (const float*)d_in[15];
    const float* W2s = (const float*)d_in[16]; const float* b2s = (const float*)d_in[17];
    const float* Wfd = (const float*)d_in[18]; const float* bfd = (const float*)d_in[19];
    const float* Wfs = (const float*)d_in[20]; const float* bfs = (const float*)d_in[21];

    const int Fd = 256, H1 = 256, H2 = 128;
    const int Nd = in_sizes[0] / Fd;
    const int Ns = in_sizes[5] / Fd;
    const int Ed = in_sizes[2];
    const int Es = in_sizes[7];

    float* out    = (float*)d_out;
    float* o_emb1 = out;
    float* o_emb2 = o_emb1 + (size_t)Nd * H2;
    float* o_e1s  = o_emb2 + (size_t)Ns * H2;
    float* o_e1f  = o_e1s  + (size_t)Nd * H2;
    float* o_e2s  = o_e1f  + (size_t)Nd * H2;
    float* o_e2f  = o_e2s  + (size_t)Ns * H2;

    char* p = (char*)d_ws;
    auto alloc = [&](size_t bytes) { char* q = p; p += (bytes + 255) & ~(size_t)255; return q; };
    ushort* x_h   = (ushort*)alloc((size_t)Nd * 256 * 2);
    ushort* xw1   = (ushort*)alloc((size_t)Nd * 256 * 2);
    ushort* hbuf  = (ushort*)alloc((size_t)Nd * 256 * 2);
    ushort* tbuf  = (ushort*)alloc((size_t)Nd * 128 * 2);
    ushort* es_h  = (ushort*)alloc((size_t)Nd * 128 * 2);
    ushort* ef_h  = (ushort*)alloc((size_t)Nd * 128 * 2);
    ushort* W1dt  = (ushort*)alloc(256 * 256 * 2);
    ushort* W2dt  = (ushort*)alloc(256 * 128 * 2);
    ushort* Wfdt  = (ushort*)alloc(256 * 128 * 2);
    ushort* W1st  = (ushort*)alloc(256 * 256 * 2);
    ushort* W2st  = (ushort*)alloc(256 * 128 * 2);
    ushort* Wfst  = (ushort*)alloc(256 * 128 * 2);
    int*    perm_src = (int*)  alloc((size_t)Ed * 4);
    float*  perm_w   = (float*)alloc((size_t)Ed * 4);
    int*    row_ptr  = (int*)  alloc((size_t)(Nd + 1) * 4);
    int*    cursor   = (int*)  alloc((size_t)Nd * 4);
    int*    bsums    = (int*)  alloc(256 * 4);

    // weight transposes (f32 -> f16 [N,K])
    transpose_f16_k<<<dim3(8, 8), 256, 0, stream>>>(W1d, W1dt, 256, 256);
    transpose_f16_k<<<dim3(8, 4), 256, 0, stream>>>(W2d, W2dt, 256, 128);
    transpose_f16_k<<<dim3(8, 4), 256, 0, stream>>>(Wfd, Wfdt, 256, 128);
    transpose_f16_k<<<dim3(8, 8), 256, 0, stream>>>(W1s, W1st, 256, 256);
    transpose_f16_k<<<dim3(8, 4), 256, 0, stream>>>(W2s, W2st, 256, 128);
    transpose_f16_k<<<dim3(8, 4), 256, 0, stream>>>(Wfs, Wfst, 256, 128);

    auto branch = [&](const float* X, int n,
                      const int* ei1, const float* w1,
                      const int* ei2, const float* w2, int E,
                      const ushort* W1t, const float* b1,
                      const ushort* W2t, const float* b2,
                      const ushort* Wft, const float* bfu,
                      float* o_sim, float* o_feat, float* o_emb) {
        f2h_vec<<<2048, 256, 0, stream>>>(X, x_h, n * 64);
        gemm_mfma<false, false, false, false><<<dim3((n + 127) / 128, 2), 256, 0, stream>>>(
            x_h, nullptr, W1t, nullptr, xw1, nullptr, n, 256, 256);
        const int*   eis[2]  = {ei1, ei2};
        const float* wss[2]  = {w1, w2};
        float*       of[2]   = {o_sim, o_feat};
        ushort*      oh[2]   = {es_h, ef_h};
        int B = (n + 1023) / 1024;
        for (int g = 0; g < 2; ++g) {
            hipMemsetAsync(cursor, 0, (size_t)n * 4, stream);
            hist_k<<<(E + 255) / 256, 256, 0, stream>>>(eis[g], E, cursor);
            scan_p1<<<B, 256, 0, stream>>>(cursor, n, bsums);
            scan_p2<<<1, 256, 0, stream>>>(bsums, B);
            scan_p3<<<B, 256, 0, stream>>>(cursor, n, E, bsums, row_ptr, cursor);
            scatter_k<<<(E + 255) / 256, 256, 0, stream>>>(eis[g], wss[g], E, cursor, perm_src, perm_w);
            spmm_f16<4, true, false><<<(n + 3) / 4, 256, 0, stream>>>(
                (const f16*)xw1, perm_src, perm_w, row_ptr, b1, hbuf, nullptr, n);
            gemm_mfma<false, false, false, false><<<dim3((n + 127) / 128, 1), 256, 0, stream>>>(
                hbuf, nullptr, W2t, nullptr, tbuf, nullptr, n, 128, 256);
            spmm_f16<2, false, true><<<(n + 3) / 4, 256, 0, stream>>>(
                (const f16*)tbuf, perm_src, perm_w, row_ptr, b2, oh[g], of[g], n);
        }
        gemm_mfma<true, true, true, true><<<dim3((n + 127) / 128, 1), 256, 0, stream>>>(
            es_h, ef_h, Wft, bfu, nullptr, o_emb, n, 128, 256);
    };

    branch(Xd, Nd, eid_sim, wd_sim, eid_feat, wd_feat, Ed,
           W1dt, b1d, W2dt, b2d, Wfdt, bfd, o_e1s, o_e1f, o_emb1);
    branch(Xs, Ns, eis_sim, ws_sim, eis_feat, ws_feat, Es,
           W1st, b1s, W2st, b2s, Wfst, bfs, o_e2s, o_e2f, o_emb2);
}

// Round 4
// 1505.400 us; speedup vs baseline: 3.3549x; 1.4806x over previous
//
#include <hip/hip_runtime.h>

typedef _Float16 f16;
typedef __attribute__((ext_vector_type(8))) _Float16 f16x8;
typedef __attribute__((ext_vector_type(4))) float f32x4;

__device__ inline ushort f2h_bits(float f) {
    f16 h = (f16)f;
    return __builtin_bit_cast(ushort, h);
}

// ---------------------------------------------------------------------------
// f32 -> f16 vectorized convert
// ---------------------------------------------------------------------------
__global__ __launch_bounds__(256) void f2h_vec(const float* __restrict__ in,
                                               ushort* __restrict__ out, int n4) {
    for (int i = blockIdx.x * 256 + threadIdx.x; i < n4; i += gridDim.x * 256) {
        float4 v = reinterpret_cast<const float4*>(in)[i];
        reinterpret_cast<ushort4*>(out)[i] =
            make_ushort4(f2h_bits(v.x), f2h_bits(v.y), f2h_bits(v.z), f2h_bits(v.w));
    }
}

// transpose + convert: W[K,N] f32 -> Wt[N,K] f16. K,N multiples of 32.
__global__ __launch_bounds__(256) void transpose_f16_k(const float* __restrict__ W,
                                                       ushort* __restrict__ Wt,
                                                       int K, int N) {
    __shared__ ushort tile[32][33];
    int k0 = blockIdx.x * 32, n0 = blockIdx.y * 32;
    int tx = threadIdx.x & 31, ty = threadIdx.x >> 5;
    #pragma unroll
    for (int i = 0; i < 32; i += 8)
        tile[ty + i][tx] = f2h_bits(W[(size_t)(k0 + ty + i) * N + n0 + tx]);
    __syncthreads();
    #pragma unroll
    for (int i = 0; i < 32; i += 8)
        Wt[(size_t)(n0 + ty + i) * K + k0 + tx] = tile[tx][ty + i];
}

// ---------------------------------------------------------------------------
// CSR build, two-level binned (buckets of 256 rows).
// Avoids the 11x cross-XCD write amplification of a flat random scatter.
// ---------------------------------------------------------------------------

// per-bucket edge counts (LDS-binned)
__global__ __launch_bounds__(256) void bucket_hist(const int* __restrict__ dst, int E,
                                                   int* __restrict__ counts) {
    __shared__ int h[512];
    int t = threadIdx.x;
    h[t] = 0; h[t + 256] = 0;
    __syncthreads();
    int e0 = blockIdx.x * 4096;
    #pragma unroll
    for (int k = 0; k < 16; ++k) {
        int i = e0 + t + k * 256;
        if (i < E) atomicAdd(&h[((uint)dst[i]) >> 8], 1);
    }
    __syncthreads();
    for (int b = t; b < 512; b += 256)
        if (h[b]) atomicAdd(&counts[b], h[b]);
}

// single block: exclusive scan of NB bucket counts -> base, cursor; row_ptr[n]=E
__global__ __launch_bounds__(256) void bucket_scan(const int* __restrict__ counts, int NB, int E,
                                                   int* __restrict__ base, int* __restrict__ cursor,
                                                   int* __restrict__ row_ptr, int n) {
    int t = threadIdx.x, lane = t & 63, wave = t >> 6;
    int v0 = (2 * t     < NB) ? counts[2 * t]     : 0;
    int v1 = (2 * t + 1 < NB) ? counts[2 * t + 1] : 0;
    int s = v0 + v1;
    int incl = s;
    for (int off = 1; off < 64; off <<= 1) {
        int u = __shfl_up(incl, off);
        if (lane >= off) incl += u;
    }
    __shared__ int wsum[4];
    if (lane == 63) wsum[wave] = incl;
    __syncthreads();
    int excl = incl - s;
    for (int wv = 0; wv < wave; ++wv) excl += wsum[wv];
    if (2 * t < NB)     { base[2 * t]     = excl;      cursor[2 * t]     = excl; }
    if (2 * t + 1 < NB) { base[2 * t + 1] = excl + v0; cursor[2 * t + 1] = excl + v0; }
    if (t == 0) { base[NB] = E; row_ptr[n] = E; }
}

// LDS-binned scatter: chunk of 4096 edges -> per-bucket contiguous runs in bst.
// record: ((src<<8)|local_row, w_bits), 8B.
__global__ __launch_bounds__(256) void scatter_binned(const int* __restrict__ ei,
                                                      const float* __restrict__ w, int E,
                                                      int* __restrict__ bucket_cursor,
                                                      int2* __restrict__ bst) {
    __shared__ int hist[512], excl[512], sbase[512], lcur[512];
    __shared__ int2 stage[4096];
    __shared__ ushort sbin[4096];
    const int t = threadIdx.x, lane = t & 63, wave = t >> 6;
    const int e0 = blockIdx.x * 4096;
    const int cnt = min(4096, E - e0);

    hist[t] = 0; hist[t + 256] = 0;
    __syncthreads();

    int   d[16], s[16];
    float wv[16];
    #pragma unroll
    for (int k = 0; k < 16; ++k) {
        int i = t + k * 256;
        if (i < cnt) {
            d[k]  = ei[e0 + i];
            s[k]  = ei[(size_t)E + e0 + i];
            wv[k] = w[e0 + i];
            atomicAdd(&hist[((uint)d[k]) >> 8], 1);
        }
    }
    __syncthreads();

    // exclusive scan over 512 bins (2 per thread)
    {
        int v0 = hist[2 * t], v1 = hist[2 * t + 1];
        int sum = v0 + v1;
        int incl = sum;
        for (int off = 1; off < 64; off <<= 1) {
            int u = __shfl_up(incl, off);
            if (lane >= off) incl += u;
        }
        __shared__ int wsum[4];
        if (lane == 63) wsum[wave] = incl;
        __syncthreads();
        int e = incl - sum;
        for (int wvv = 0; wvv < wave; ++wvv) e += wsum[wvv];
        excl[2 * t] = e; excl[2 * t + 1] = e + v0;
    }
    __syncthreads();

    // reserve global space per bin; init local cursors
    for (int b = t; b < 512; b += 256) {
        int c = hist[b];
        sbase[b] = c ? atomicAdd(&bucket_cursor[b], c) : 0;
        lcur[b] = excl[b];
    }
    __syncthreads();

    // stage records grouped by bin
    #pragma unroll
    for (int k = 0; k < 16; ++k) {
        int i = t + k * 256;
        if (i < cnt) {
            int bin = ((uint)d[k]) >> 8;
            int pos = atomicAdd(&lcur[bin], 1);
            stage[pos] = make_int2((s[k] << 8) | (d[k] & 255), __float_as_int(wv[k]));
            sbin[pos] = (ushort)bin;
        }
    }
    __syncthreads();

    // coalesced-run copy out
    #pragma unroll
    for (int k = 0; k < 16; ++k) {
        int i = t + k * 256;
        if (i < cnt) {
            int2 r = stage[i];
            int bin = sbin[i];
            bst[(size_t)sbase[bin] + i - excl[bin]] = r;
        }
    }
}

// one block per bucket: local row hist/scan -> row_ptr + exact perm placement.
__global__ __launch_bounds__(256) void bucket_finalize(const int2* __restrict__ bst,
                                                       const int* __restrict__ base,
                                                       int* __restrict__ row_ptr,
                                                       int2* __restrict__ perm, int n) {
    __shared__ int hist[256], cur[256], wsum[4];
    const int b = blockIdx.x, t = threadIdx.x, lane = t & 63, wave = t >> 6;
    const int lo = base[b], hi = base[b + 1];
    hist[t] = 0;
    __syncthreads();
    for (int i = lo + t; i < hi; i += 256)
        atomicAdd(&hist[bst[i].x & 255], 1);
    __syncthreads();
    int v = hist[t];
    int incl = v;
    for (int off = 1; off < 64; off <<= 1) {
        int u = __shfl_up(incl, off);
        if (lane >= off) incl += u;
    }
    if (lane == 63) wsum[wave] = incl;
    __syncthreads();
    int excl = incl - v;
    for (int wv = 0; wv < wave; ++wv) excl += wsum[wv];
    const int r0 = b << 8;
    const int nrows = min(256, n - r0);
    if (t < nrows) row_ptr[r0 + t] = lo + excl;
    cur[t] = lo + excl;
    __syncthreads();
    for (int i = lo + t; i < hi; i += 256) {
        int2 r = bst[i];
        int local = r.x & 255;
        int slot = atomicAdd(&cur[local], 1);
        perm[slot] = make_int2(r.x >> 8, r.y);
    }
}

// ---------------------------------------------------------------------------
// SpMM over f16 table: out[row,:] = sum_e w_e * x[src_e,:] (+bias)(relu)
// one wave per row, F = 64*C. Edge records broadcast via readlane -> SGPR.
// ---------------------------------------------------------------------------
template<int C, bool RELU, bool DUAL>
__global__ __launch_bounds__(256) void spmm_f16(
    const f16* __restrict__ x,
    const int2* __restrict__ perm,
    const int* __restrict__ row_ptr, const float* __restrict__ bias,
    ushort* __restrict__ out_h, float* __restrict__ out_f, int n)
{
    const int wave = threadIdx.x >> 6, lane = threadIdx.x & 63;
    const int row = blockIdx.x * 4 + wave;
    if (row >= n) return;
    const int F = 64 * C;
    const int e0 = row_ptr[row], e1 = row_ptr[row + 1];
    float acc[C] = {};
    const int laneoff = lane * C;

    for (int eb = e0; eb < e1; eb += 64) {
        int idx = eb + lane;
        int myS = 0; int myW = 0;
        if (idx < e1) { int2 rec = perm[idx]; myS = rec.x; myW = rec.y; }
        int m = min(64, e1 - eb);
        for (int j0 = 0; j0 < m; j0 += 8) {
            #pragma unroll
            for (int u = 0; u < 8; ++u) {
                int j = j0 + u;   // padded lanes carry w=0
                int   s = __builtin_amdgcn_readlane(myS, j);
                float w = __int_as_float(__builtin_amdgcn_readlane(myW, j));
                const f16* xr = x + (size_t)((uint)s * (uint)F) + laneoff;
                if (C == 4) {
                    union { uint2 u2; f16 h[4]; } cv;
                    cv.u2 = *reinterpret_cast<const uint2*>(xr);
                    acc[0] = fmaf((float)cv.h[0], w, acc[0]);
                    acc[1] = fmaf((float)cv.h[1], w, acc[1]);
                    acc[2] = fmaf((float)cv.h[2], w, acc[2]);
                    acc[3] = fmaf((float)cv.h[3], w, acc[3]);
                } else {
                    union { uint u1; f16 h[2]; } cv;
                    cv.u1 = *reinterpret_cast<const uint*>(xr);
                    acc[0] = fmaf((float)cv.h[0], w, acc[0]);
                    acc[1] = fmaf((float)cv.h[1], w, acc[1]);
                }
            }
        }
    }

    #pragma unroll
    for (int c = 0; c < C; ++c) {
        float v = acc[c] + bias[laneoff + c];
        acc[c] = RELU ? fmaxf(v, 0.f) : v;
    }
    size_t ob = (size_t)row * F + laneoff;
    if (DUAL) {
        if (C == 4) *reinterpret_cast<float4*>(out_f + ob) = make_float4(acc[0], acc[1], acc[2], acc[3]);
        else        *reinterpret_cast<float2*>(out_f + ob) = make_float2(acc[0], acc[1]);
    }
    if (C == 4) *reinterpret_cast<ushort4*>(out_h + ob) =
        make_ushort4(f2h_bits(acc[0]), f2h_bits(acc[1]), f2h_bits(acc[2]), f2h_bits(acc[3]));
    else        *reinterpret_cast<ushort2*>(out_h + ob) =
        make_ushort2(f2h_bits(acc[0]), f2h_bits(acc[1]));
}

// ---------------------------------------------------------------------------
// f16 MFMA GEMM: C[M,N] = A[M,K] @ Bt[N,K]^T, 128x128 tile, BK=32, 4 waves.
// ---------------------------------------------------------------------------
template<bool FUSE, bool RELU, bool BIAS, bool F32OUT>
__global__ __launch_bounds__(256) void gemm_mfma(
    const ushort* __restrict__ A, const ushort* __restrict__ A2,
    const ushort* __restrict__ Bt, const float* __restrict__ bias,
    ushort* __restrict__ Ch, float* __restrict__ Cf,
    int M, int N, int K)
{
    __shared__ ushort Asb[128 * 32];
    __shared__ ushort Bsb[128 * 32];
    const int tid = threadIdx.x;
    const int lane = tid & 63, wave = tid >> 6;
    const int wr = wave >> 1, wc = wave & 1;
    const int bm = blockIdx.x * 128, bn = blockIdx.y * 128;

    f32x4 acc[4][4] = {};

    for (int k0 = 0; k0 < K; k0 += 32) {
        #pragma unroll
        for (int h = 0; h < 2; ++h) {
            int slot = tid + 256 * h;
            int r = slot >> 2, cb = slot & 3;
            int row = bm + r;
            uint4 v = make_uint4(0, 0, 0, 0);
            if (row < M) {
                int kk = k0 + cb * 8;
                if (FUSE) {
                    const ushort* Ap = (kk < 128) ? A : A2;
                    v = *reinterpret_cast<const uint4*>(Ap + (size_t)row * 128 + (kk & 127));
                } else {
                    v = *reinterpret_cast<const uint4*>(A + (size_t)row * K + kk);
                }
            }
            int scb = cb ^ ((r >> 1) & 3);
            *reinterpret_cast<uint4*>(&Asb[r * 32 + scb * 8]) = v;
        }
        #pragma unroll
        for (int h = 0; h < 2; ++h) {
            int slot = tid + 256 * h;
            int r = slot >> 2, cb = slot & 3;
            uint4 v = *reinterpret_cast<const uint4*>(Bt + (size_t)(bn + r) * K + k0 + cb * 8);
            int scb = cb ^ ((r >> 1) & 3);
            *reinterpret_cast<uint4*>(&Bsb[r * 32 + scb * 8]) = v;
        }
        __syncthreads();

        f16x8 fa[4], fb[4];
        #pragma unroll
        for (int i = 0; i < 4; ++i) {
            int r = wr * 64 + i * 16 + (lane & 15);
            int scb = (lane >> 4) ^ ((r >> 1) & 3);
            fa[i] = *reinterpret_cast<const f16x8*>(&Asb[r * 32 + scb * 8]);
        }
        #pragma unroll
        for (int j = 0; j < 4; ++j) {
            int r = wc * 64 + j * 16 + (lane & 15);
            int scb = (lane >> 4) ^ ((r >> 1) & 3);
            fb[j] = *reinterpret_cast<const f16x8*>(&Bsb[r * 32 + scb * 8]);
        }
        #pragma unroll
        for (int i = 0; i < 4; ++i)
            #pragma unroll
            for (int j = 0; j < 4; ++j)
                acc[i][j] = __builtin_amdgcn_mfma_f32_16x16x32_f16(fa[i], fb[j], acc[i][j], 0, 0, 0);
        __syncthreads();
    }

    #pragma unroll
    for (int i = 0; i < 4; ++i) {
        #pragma unroll
        for (int r4 = 0; r4 < 4; ++r4) {
            int row = bm + wr * 64 + i * 16 + (lane >> 4) * 4 + r4;
            if (row >= M) continue;
            #pragma unroll
            for (int j = 0; j < 4; ++j) {
                int col = bn + wc * 64 + j * 16 + (lane & 15);
                float v = acc[i][j][r4];
                if (BIAS) v += bias[col];
                if (RELU) v = fmaxf(v, 0.f);
                if (F32OUT) Cf[(size_t)row * N + col] = v;
                else        Ch[(size_t)row * N + col] = f2h_bits(v);
            }
        }
    }
}

// ---------------------------------------------------------------------------
// Orchestration
// ---------------------------------------------------------------------------
extern "C" void kernel_launch(void* const* d_in, const int* in_sizes, int n_in,
                              void* d_out, int out_size, void* d_ws, size_t ws_size,
                              hipStream_t stream) {
    const float* Xd       = (const float*)d_in[0];
    const int*   eid_sim  = (const int*)  d_in[1];
    const float* wd_sim   = (const float*)d_in[2];
    const int*   eid_feat = (const int*)  d_in[3];
    const float* wd_feat  = (const float*)d_in[4];
    const float* Xs       = (const float*)d_in[5];
    const int*   eis_sim  = (const int*)  d_in[6];
    const float* ws_sim   = (const float*)d_in[7];
    const int*   eis_feat = (const int*)  d_in[8];
    const float* ws_feat  = (const float*)d_in[9];
    const float* W1d = (const float*)d_in[10]; const float* b1d = (const float*)d_in[11];
    const float* W2d = (const float*)d_in[12]; const float* b2d = (const float*)d_in[13];
    const float* W1s = (const float*)d_in[14]; const float* b1s = (const float*)d_in[15];
    const float* W2s = (const float*)d_in[16]; const float* b2s = (const float*)d_in[17];
    const float* Wfd = (const float*)d_in[18]; const float* bfd = (const float*)d_in[19];
    const float* Wfs = (const float*)d_in[20]; const float* bfs = (const float*)d_in[21];

    const int Fd = 256, H1 = 256, H2 = 128;
    const int Nd = in_sizes[0] / Fd;
    const int Ns = in_sizes[5] / Fd;
    const int Ed = in_sizes[2];
    const int Es = in_sizes[7];

    float* out    = (float*)d_out;
    float* o_emb1 = out;
    float* o_emb2 = o_emb1 + (size_t)Nd * H2;
    float* o_e1s  = o_emb2 + (size_t)Ns * H2;
    float* o_e1f  = o_e1s  + (size_t)Nd * H2;
    float* o_e2s  = o_e1f  + (size_t)Nd * H2;
    float* o_e2f  = o_e2s  + (size_t)Ns * H2;

    char* p = (char*)d_ws;
    auto alloc = [&](size_t bytes) { char* q = p; p += (bytes + 255) & ~(size_t)255; return q; };
    ushort* x_h   = (ushort*)alloc((size_t)Nd * 256 * 2);
    ushort* xw1   = (ushort*)alloc((size_t)Nd * 256 * 2);
    ushort* hbuf  = (ushort*)alloc((size_t)Nd * 256 * 2);
    ushort* tbuf  = (ushort*)alloc((size_t)Nd * 128 * 2);
    ushort* es_h  = (ushort*)alloc((size_t)Nd * 128 * 2);
    ushort* ef_h  = (ushort*)alloc((size_t)Nd * 128 * 2);
    ushort* W1dt  = (ushort*)alloc(256 * 256 * 2);
    ushort* W2dt  = (ushort*)alloc(256 * 128 * 2);
    ushort* Wfdt  = (ushort*)alloc(256 * 128 * 2);
    ushort* W1st  = (ushort*)alloc(256 * 256 * 2);
    ushort* W2st  = (ushort*)alloc(256 * 128 * 2);
    ushort* Wfst  = (ushort*)alloc(256 * 128 * 2);
    int2*   perm     = (int2*)alloc((size_t)Ed * 8);
    int*    row_ptr  = (int*) alloc((size_t)(Nd + 1) * 4);
    int*    bcounts  = (int*) alloc(512 * 4);
    int*    bbase    = (int*) alloc(513 * 4);
    int*    bcursor  = (int*) alloc(512 * 4);
    // bst aliases hbuf+tbuf (dead during CSR build; Ed*8 <= Nd*256*2)
    int2*   bst      = (int2*)hbuf;

    transpose_f16_k<<<dim3(8, 8), 256, 0, stream>>>(W1d, W1dt, 256, 256);
    transpose_f16_k<<<dim3(8, 4), 256, 0, stream>>>(W2d, W2dt, 256, 128);
    transpose_f16_k<<<dim3(8, 4), 256, 0, stream>>>(Wfd, Wfdt, 256, 128);
    transpose_f16_k<<<dim3(8, 8), 256, 0, stream>>>(W1s, W1st, 256, 256);
    transpose_f16_k<<<dim3(8, 4), 256, 0, stream>>>(W2s, W2st, 256, 128);
    transpose_f16_k<<<dim3(8, 4), 256, 0, stream>>>(Wfs, Wfst, 256, 128);

    auto branch = [&](const float* X, int n,
                      const int* ei1, const float* w1,
                      const int* ei2, const float* w2, int E,
                      const ushort* W1t, const float* b1,
                      const ushort* W2t, const float* b2,
                      const ushort* Wft, const float* bfu,
                      float* o_sim, float* o_feat, float* o_emb) {
        const int NB = (n + 255) >> 8;
        const int EB = (E + 4095) / 4096;
        f2h_vec<<<2048, 256, 0, stream>>>(X, x_h, n * 64);
        gemm_mfma<false, false, false, false><<<dim3((n + 127) / 128, 2), 256, 0, stream>>>(
            x_h, nullptr, W1t, nullptr, xw1, nullptr, n, 256, 256);
        const int*   eis[2]  = {ei1, ei2};
        const float* wss[2]  = {w1, w2};
        float*       of[2]   = {o_sim, o_feat};
        ushort*      oh[2]   = {es_h, ef_h};
        for (int g = 0; g < 2; ++g) {
            hipMemsetAsync(bcounts, 0, 512 * 4, stream);
            bucket_hist<<<EB, 256, 0, stream>>>(eis[g], E, bcounts);
            bucket_scan<<<1, 256, 0, stream>>>(bcounts, NB, E, bbase, bcursor, row_ptr, n);
            scatter_binned<<<EB, 256, 0, stream>>>(eis[g], wss[g], E, bcursor, bst);
            bucket_finalize<<<NB, 256, 0, stream>>>(bst, bbase, row_ptr, perm, n);
            spmm_f16<4, true, false><<<(n + 3) / 4, 256, 0, stream>>>(
                (const f16*)xw1, perm, row_ptr, b1, hbuf, nullptr, n);
            gemm_mfma<false, false, false, false><<<dim3((n + 127) / 128, 1), 256, 0, stream>>>(
                hbuf, nullptr, W2t, nullptr, tbuf, nullptr, n, 128, 256);
            spmm_f16<2, false, true><<<(n + 3) / 4, 256, 0, stream>>>(
                (const f16*)tbuf, perm, row_ptr, b2, oh[g], of[g], n);
        }
        gemm_mfma<true, true, true, true><<<dim3((n + 127) / 128, 1), 256, 0, stream>>>(
            es_h, ef_h, Wft, bfu, nullptr, o_emb, n, 128, 256);
    };

    branch(Xd, Nd, eid_sim, wd_sim, eid_feat, wd_feat, Ed,
           W1dt, b1d, W2dt, b2d, Wfdt, bfd, o_e1s, o_e1f, o_emb1);
    branch(Xs, Ns, eis_sim, ws_sim, eis_feat, ws_feat, Es,
           W1st, b1s, W2st, b2s, Wfst, bfs, o_e2s, o_e2f, o_emb2);
}

// Round 5
// 1384.489 us; speedup vs baseline: 3.6479x; 1.0873x over previous
//
#include <hip/hip_runtime.h>

typedef _Float16 f16;
typedef __attribute__((ext_vector_type(8))) _Float16 f16x8;
typedef __attribute__((ext_vector_type(4))) float f32x4;

__device__ inline ushort f2h_bits(float f) {
    f16 h = (f16)f;
    return __builtin_bit_cast(ushort, h);
}

// ---------------------------------------------------------------------------
// Batched weight transpose+convert: W[K,N] f32 -> Wt[N,K] f16, 6 weights.
// ---------------------------------------------------------------------------
struct T6 {
    const float* s[6];
    ushort* d[6];
    int N[6];
};

__global__ __launch_bounds__(256) void transpose6_k(T6 a) {
    __shared__ ushort tile[32][33];
    const int z = blockIdx.z;
    const int K = 256, N = a.N[z];
    int k0 = blockIdx.x * 32, n0 = blockIdx.y * 32;
    if (n0 >= N) return;
    const float* W = a.s[z];
    ushort* Wt = a.d[z];
    int tx = threadIdx.x & 31, ty = threadIdx.x >> 5;
    #pragma unroll
    for (int i = 0; i < 32; i += 8)
        tile[ty + i][tx] = f2h_bits(W[(size_t)(k0 + ty + i) * N + n0 + tx]);
    __syncthreads();
    #pragma unroll
    for (int i = 0; i < 32; i += 8)
        Wt[(size_t)(n0 + ty + i) * K + k0 + tx] = tile[tx][ty + i];
}

// ---------------------------------------------------------------------------
// Batched CSR build (4 graphs), two-level binned (buckets of 256 rows).
// ---------------------------------------------------------------------------
struct GraphDesc {
    const int* ei;      // [2,E]: dst = ei[0..E), src = ei[E..2E)
    const float* w;
    int E, n, NB, bstoff;
    int* row_ptr;       // [n+1]
    int2* perm;         // [E] (src, w_bits)
};
struct G4 { GraphDesc g[4]; };

__global__ __launch_bounds__(256) void hist_b(G4 a, int* __restrict__ bcounts) {
    const GraphDesc& G = a.g[blockIdx.y];
    const int e0 = blockIdx.x * 4096;
    if (e0 >= G.E) return;
    __shared__ int h[512];
    int t = threadIdx.x;
    h[t] = 0; h[t + 256] = 0;
    __syncthreads();
    #pragma unroll
    for (int k = 0; k < 16; ++k) {
        int i = e0 + t + k * 256;
        if (i < G.E) atomicAdd(&h[((uint)G.ei[i]) >> 8], 1);
    }
    __syncthreads();
    int* bc = bcounts + blockIdx.y * 512;
    for (int b = t; b < 512; b += 256)
        if (h[b]) atomicAdd(&bc[b], h[b]);
}

// one block per graph: exclusive scan of 512 bins -> base, cursor; row_ptr[n]=E
__global__ __launch_bounds__(256) void scan_b(G4 a, const int* __restrict__ bcounts,
                                              int* __restrict__ bbase, int* __restrict__ bcursor) {
    const int gidx = blockIdx.x;
    const GraphDesc& G = a.g[gidx];
    const int* bc = bcounts + gidx * 512;
    int* base = bbase + gidx * 513;
    int* cur  = bcursor + gidx * 512;
    int t = threadIdx.x, lane = t & 63, wave = t >> 6;
    int v0 = bc[2 * t], v1 = bc[2 * t + 1];
    int s = v0 + v1;
    int incl = s;
    for (int off = 1; off < 64; off <<= 1) {
        int u = __shfl_up(incl, off);
        if (lane >= off) incl += u;
    }
    __shared__ int wsum[4];
    if (lane == 63) wsum[wave] = incl;
    __syncthreads();
    int excl = incl - s;
    for (int wv = 0; wv < wave; ++wv) excl += wsum[wv];
    base[2 * t] = excl;      cur[2 * t] = excl;
    base[2 * t + 1] = excl + v0; cur[2 * t + 1] = excl + v0;
    if (t == 0) { base[512] = G.E; G.row_ptr[G.n] = G.E; }
}

// LDS-binned scatter: chunk of 4096 edges -> per-bucket contiguous runs in bst.
__global__ __launch_bounds__(256) void scatter_b(G4 a, int* __restrict__ bcursor,
                                                 int2* __restrict__ bst) {
    const GraphDesc& G = a.g[blockIdx.y];
    const int e0 = blockIdx.x * 4096;
    if (e0 >= G.E) return;
    __shared__ int hist[512], excl[512], sbase[512], lcur[512];
    __shared__ int2 stage[4096];
    __shared__ ushort sbin[4096];
    const int t = threadIdx.x, lane = t & 63, wave = t >> 6;
    const int cnt = min(4096, G.E - e0);
    int* bcur = bcursor + blockIdx.y * 512;

    hist[t] = 0; hist[t + 256] = 0;
    __syncthreads();

    int   d[16], s[16];
    float wv[16];
    #pragma unroll
    for (int k = 0; k < 16; ++k) {
        int i = t + k * 256;
        if (i < cnt) {
            d[k]  = G.ei[e0 + i];
            s[k]  = G.ei[(size_t)G.E + e0 + i];
            wv[k] = G.w[e0 + i];
            atomicAdd(&hist[((uint)d[k]) >> 8], 1);
        }
    }
    __syncthreads();

    {
        int v0 = hist[2 * t], v1 = hist[2 * t + 1];
        int sum = v0 + v1;
        int incl = sum;
        for (int off = 1; off < 64; off <<= 1) {
            int u = __shfl_up(incl, off);
            if (lane >= off) incl += u;
        }
        __shared__ int wsum[4];
        if (lane == 63) wsum[wave] = incl;
        __syncthreads();
        int e = incl - sum;
        for (int wvv = 0; wvv < wave; ++wvv) e += wsum[wvv];
        excl[2 * t] = e; excl[2 * t + 1] = e + v0;
    }
    __syncthreads();

    for (int b = t; b < 512; b += 256) {
        int c = hist[b];
        sbase[b] = c ? atomicAdd(&bcur[b], c) : 0;
        lcur[b] = excl[b];
    }
    __syncthreads();

    #pragma unroll
    for (int k = 0; k < 16; ++k) {
        int i = t + k * 256;
        if (i < cnt) {
            int bin = ((uint)d[k]) >> 8;
            int pos = atomicAdd(&lcur[bin], 1);
            stage[pos] = make_int2((s[k] << 8) | (d[k] & 255), __float_as_int(wv[k]));
            sbin[pos] = (ushort)bin;
        }
    }
    __syncthreads();

    #pragma unroll
    for (int k = 0; k < 16; ++k) {
        int i = t + k * 256;
        if (i < cnt) {
            int2 r = stage[i];
            int bin = sbin[i];
            bst[(size_t)G.bstoff + sbase[bin] + i - excl[bin]] = r;
        }
    }
}

// one block per bucket: local row hist/scan -> row_ptr + exact perm placement.
__global__ __launch_bounds__(256) void finalize_b(G4 a, const int* __restrict__ bbase,
                                                  const int2* __restrict__ bst) {
    const GraphDesc& G = a.g[blockIdx.y];
    const int b = blockIdx.x;
    if (b >= G.NB) return;
    __shared__ int hist[256], cur[256], wsum[4];
    const int t = threadIdx.x, lane = t & 63, wave = t >> 6;
    const int* base = bbase + blockIdx.y * 513;
    const int lo = base[b], hi = base[b + 1];
    const int2* bg = bst + G.bstoff;
    hist[t] = 0;
    __syncthreads();
    for (int i = lo + t; i < hi; i += 256)
        atomicAdd(&hist[bg[i].x & 255], 1);
    __syncthreads();
    int v = hist[t];
    int incl = v;
    for (int off = 1; off < 64; off <<= 1) {
        int u = __shfl_up(incl, off);
        if (lane >= off) incl += u;
    }
    if (lane == 63) wsum[wave] = incl;
    __syncthreads();
    int excl = incl - v;
    for (int wv = 0; wv < wave; ++wv) excl += wsum[wv];
    const int r0 = b << 8;
    const int nrows = min(256, G.n - r0);
    if (t < nrows) G.row_ptr[r0 + t] = lo + excl;
    cur[t] = lo + excl;
    __syncthreads();
    for (int i = lo + t; i < hi; i += 256) {
        int2 r = bg[i];
        int local = r.x & 255;
        int slot = atomicAdd(&cur[local], 1);
        G.perm[slot] = make_int2(r.x >> 8, r.y);
    }
}

// ---------------------------------------------------------------------------
// SpMM over f16 table: out[row,:] = sum_e w_e * x[src_e,:] (+bias)(relu)
// one wave per row, F = 64*C. Edge records broadcast via readlane -> SGPR.
// ---------------------------------------------------------------------------
template<int C, bool RELU, bool DUAL>
__global__ __launch_bounds__(256) void spmm_f16(
    const f16* __restrict__ x,
    const int2* __restrict__ perm,
    const int* __restrict__ row_ptr, const float* __restrict__ bias,
    ushort* __restrict__ out_h, float* __restrict__ out_f, int n)
{
    const int wave = threadIdx.x >> 6, lane = threadIdx.x & 63;
    const int row = blockIdx.x * 4 + wave;
    if (row >= n) return;
    const int F = 64 * C;
    const int e0 = row_ptr[row], e1 = row_ptr[row + 1];
    float acc[C] = {};
    const int laneoff = lane * C;

    for (int eb = e0; eb < e1; eb += 64) {
        int idx = eb + lane;
        int myS = 0; int myW = 0;
        if (idx < e1) { int2 rec = perm[idx]; myS = rec.x; myW = rec.y; }
        int m = min(64, e1 - eb);
        for (int j0 = 0; j0 < m; j0 += 8) {
            #pragma unroll
            for (int u = 0; u < 8; ++u) {
                int j = j0 + u;   // padded lanes carry w=0
                int   s = __builtin_amdgcn_readlane(myS, j);
                float w = __int_as_float(__builtin_amdgcn_readlane(myW, j));
                const f16* xr = x + (size_t)((uint)s * (uint)F) + laneoff;
                if (C == 4) {
                    union { uint2 u2; f16 h[4]; } cv;
                    cv.u2 = *reinterpret_cast<const uint2*>(xr);
                    acc[0] = fmaf((float)cv.h[0], w, acc[0]);
                    acc[1] = fmaf((float)cv.h[1], w, acc[1]);
                    acc[2] = fmaf((float)cv.h[2], w, acc[2]);
                    acc[3] = fmaf((float)cv.h[3], w, acc[3]);
                } else {
                    union { uint u1; f16 h[2]; } cv;
                    cv.u1 = *reinterpret_cast<const uint*>(xr);
                    acc[0] = fmaf((float)cv.h[0], w, acc[0]);
                    acc[1] = fmaf((float)cv.h[1], w, acc[1]);
                }
            }
        }
    }

    #pragma unroll
    for (int c = 0; c < C; ++c) {
        float v = acc[c] + bias[laneoff + c];
        acc[c] = RELU ? fmaxf(v, 0.f) : v;
    }
    size_t ob = (size_t)row * F + laneoff;
    if (DUAL) {
        if (C == 4) *reinterpret_cast<float4*>(out_f + ob) = make_float4(acc[0], acc[1], acc[2], acc[3]);
        else        *reinterpret_cast<float2*>(out_f + ob) = make_float2(acc[0], acc[1]);
    }
    if (C == 4) *reinterpret_cast<ushort4*>(out_h + ob) =
        make_ushort4(f2h_bits(acc[0]), f2h_bits(acc[1]), f2h_bits(acc[2]), f2h_bits(acc[3]));
    else        *reinterpret_cast<ushort2*>(out_h + ob) =
        make_ushort2(f2h_bits(acc[0]), f2h_bits(acc[1]));
}

// ---------------------------------------------------------------------------
// f16 MFMA GEMM: C[M,N] = A[M,K] @ Bt[N,K]^T, 128x128 tile, BK=32, 4 waves.
// CVTA: A is f32, converted inline during LDS staging.
// FUSE: A-operand is concat([A,A2],axis=1), each [M,128], K=256.
// ---------------------------------------------------------------------------
template<bool CVTA, bool FUSE, bool RELU, bool BIAS, bool F32OUT>
__global__ __launch_bounds__(256) void gemm_mfma(
    const void* __restrict__ Av, const ushort* __restrict__ A2,
    const ushort* __restrict__ Bt, const float* __restrict__ bias,
    ushort* __restrict__ Ch, float* __restrict__ Cf,
    int M, int N, int K)
{
    __shared__ ushort Asb[128 * 32];
    __shared__ ushort Bsb[128 * 32];
    const int tid = threadIdx.x;
    const int lane = tid & 63, wave = tid >> 6;
    const int wr = wave >> 1, wc = wave & 1;
    const int bm = blockIdx.x * 128, bn = blockIdx.y * 128;

    f32x4 acc[4][4] = {};

    for (int k0 = 0; k0 < K; k0 += 32) {
        #pragma unroll
        for (int h = 0; h < 2; ++h) {
            int slot = tid + 256 * h;
            int r = slot >> 2, cb = slot & 3;
            int row = bm + r;
            uint4 v = make_uint4(0, 0, 0, 0);
            if (row < M) {
                int kk = k0 + cb * 8;
                if (CVTA) {
                    const float* Af = (const float*)Av;
                    float4 lo = *reinterpret_cast<const float4*>(Af + (size_t)row * K + kk);
                    float4 hi = *reinterpret_cast<const float4*>(Af + (size_t)row * K + kk + 4);
                    ushort h8[8] = { f2h_bits(lo.x), f2h_bits(lo.y), f2h_bits(lo.z), f2h_bits(lo.w),
                                     f2h_bits(hi.x), f2h_bits(hi.y), f2h_bits(hi.z), f2h_bits(hi.w) };
                    v = *reinterpret_cast<const uint4*>(h8);
                } else if (FUSE) {
                    const ushort* Ap = (kk < 128) ? (const ushort*)Av : A2;
                    v = *reinterpret_cast<const uint4*>(Ap + (size_t)row * 128 + (kk & 127));
                } else {
                    v = *reinterpret_cast<const uint4*>((const ushort*)Av + (size_t)row * K + kk);
                }
            }
            int scb = cb ^ ((r >> 1) & 3);
            *reinterpret_cast<uint4*>(&Asb[r * 32 + scb * 8]) = v;
        }
        #pragma unroll
        for (int h = 0; h < 2; ++h) {
            int slot = tid + 256 * h;
            int r = slot >> 2, cb = slot & 3;
            uint4 v = *reinterpret_cast<const uint4*>(Bt + (size_t)(bn + r) * K + k0 + cb * 8);
            int scb = cb ^ ((r >> 1) & 3);
            *reinterpret_cast<uint4*>(&Bsb[r * 32 + scb * 8]) = v;
        }
        __syncthreads();

        f16x8 fa[4], fb[4];
        #pragma unroll
        for (int i = 0; i < 4; ++i) {
            int r = wr * 64 + i * 16 + (lane & 15);
            int scb = (lane >> 4) ^ ((r >> 1) & 3);
            fa[i] = *reinterpret_cast<const f16x8*>(&Asb[r * 32 + scb * 8]);
        }
        #pragma unroll
        for (int j = 0; j < 4; ++j) {
            int r = wc * 64 + j * 16 + (lane & 15);
            int scb = (lane >> 4) ^ ((r >> 1) & 3);
            fb[j] = *reinterpret_cast<const f16x8*>(&Bsb[r * 32 + scb * 8]);
        }
        #pragma unroll
        for (int i = 0; i < 4; ++i)
            #pragma unroll
            for (int j = 0; j < 4; ++j)
                acc[i][j] = __builtin_amdgcn_mfma_f32_16x16x32_f16(fa[i], fb[j], acc[i][j], 0, 0, 0);
        __syncthreads();
    }

    #pragma unroll
    for (int i = 0; i < 4; ++i) {
        #pragma unroll
        for (int r4 = 0; r4 < 4; ++r4) {
            int row = bm + wr * 64 + i * 16 + (lane >> 4) * 4 + r4;
            if (row >= M) continue;
            #pragma unroll
            for (int j = 0; j < 4; ++j) {
                int col = bn + wc * 64 + j * 16 + (lane & 15);
                float v = acc[i][j][r4];
                if (BIAS) v += bias[col];
                if (RELU) v = fmaxf(v, 0.f);
                if (F32OUT) Cf[(size_t)row * N + col] = v;
                else        Ch[(size_t)row * N + col] = f2h_bits(v);
            }
        }
    }
}

// ---------------------------------------------------------------------------
// Orchestration
// ---------------------------------------------------------------------------
extern "C" void kernel_launch(void* const* d_in, const int* in_sizes, int n_in,
                              void* d_out, int out_size, void* d_ws, size_t ws_size,
                              hipStream_t stream) {
    const float* Xd       = (const float*)d_in[0];
    const int*   eid_sim  = (const int*)  d_in[1];
    const float* wd_sim   = (const float*)d_in[2];
    const int*   eid_feat = (const int*)  d_in[3];
    const float* wd_feat  = (const float*)d_in[4];
    const float* Xs       = (const float*)d_in[5];
    const int*   eis_sim  = (const int*)  d_in[6];
    const float* ws_sim   = (const float*)d_in[7];
    const int*   eis_feat = (const int*)  d_in[8];
    const float* ws_feat  = (const float*)d_in[9];
    const float* W1d = (const float*)d_in[10]; const float* b1d = (const float*)d_in[11];
    const float* W2d = (const float*)d_in[12]; const float* b2d = (const float*)d_in[13];
    const float* W1s = (const float*)d_in[14]; const float* b1s = (const float*)d_in[15];
    const float* W2s = (const float*)d_in[16]; const float* b2s = (const float*)d_in[17];
    const float* Wfd = (const float*)d_in[18]; const float* bfd = (const float*)d_in[19];
    const float* Wfs = (const float*)d_in[20]; const float* bfs = (const float*)d_in[21];

    const int Fd = 256, H1 = 256, H2 = 128;
    const int Nd = in_sizes[0] / Fd;
    const int Ns = in_sizes[5] / Fd;
    const int Ed = in_sizes[2];
    const int Es = in_sizes[7];

    float* out    = (float*)d_out;
    float* o_emb1 = out;
    float* o_emb2 = o_emb1 + (size_t)Nd * H2;
    float* o_e1s  = o_emb2 + (size_t)Ns * H2;
    float* o_e1f  = o_e1s  + (size_t)Nd * H2;
    float* o_e2s  = o_e1f  + (size_t)Nd * H2;
    float* o_e2f  = o_e2s  + (size_t)Ns * H2;

    char* p = (char*)d_ws;
    auto alloc = [&](size_t bytes) { char* q = p; p += (bytes + 255) & ~(size_t)255; return q; };
    ushort* xw1   = (ushort*)alloc((size_t)Nd * 256 * 2);
    ushort* hbuf  = (ushort*)alloc((size_t)Nd * 256 * 2);
    ushort* tbuf  = (ushort*)alloc((size_t)Nd * 128 * 2);
    ushort* es_h  = (ushort*)alloc((size_t)Nd * 128 * 2);
    ushort* ef_h  = (ushort*)alloc((size_t)Nd * 128 * 2);
    ushort* W1dt  = (ushort*)alloc(256 * 256 * 2);
    ushort* W2dt  = (ushort*)alloc(256 * 128 * 2);
    ushort* Wfdt  = (ushort*)alloc(256 * 128 * 2);
    ushort* W1st  = (ushort*)alloc(256 * 256 * 2);
    ushort* W2st  = (ushort*)alloc(256 * 128 * 2);
    ushort* Wfst  = (ushort*)alloc(256 * 128 * 2);
    int2*   perm0 = (int2*)alloc((size_t)Ed * 8);
    int2*   perm1 = (int2*)alloc((size_t)Ed * 8);
    int2*   perm2 = (int2*)alloc((size_t)Es * 8);
    int2*   perm3 = (int2*)alloc((size_t)Es * 8);
    int*    rp0   = (int*) alloc((size_t)(Nd + 1) * 4);
    int*    rp1   = (int*) alloc((size_t)(Nd + 1) * 4);
    int*    rp2   = (int*) alloc((size_t)(Ns + 1) * 4);
    int*    rp3   = (int*) alloc((size_t)(Ns + 1) * 4);
    int*    bcounts = (int*)alloc(4 * 512 * 4);
    int*    bbase   = (int*)alloc(4 * 513 * 4);
    int*    bcursor = (int*)alloc(4 * 512 * 4);
    // bst aliases xw1+hbuf (dead during CSR build; 2*(Ed+Es)*8 <= 2*Nd*256*2)
    int2*   bst     = (int2*)xw1;

    // ---- batched weight transposes ----
    {
        T6 a;
        a.s[0] = W1d; a.s[1] = W2d; a.s[2] = Wfd; a.s[3] = W1s; a.s[4] = W2s; a.s[5] = Wfs;
        a.d[0] = W1dt; a.d[1] = W2dt; a.d[2] = Wfdt; a.d[3] = W1st; a.d[4] = W2st; a.d[5] = Wfst;
        a.N[0] = 256; a.N[1] = 128; a.N[2] = 128; a.N[3] = 256; a.N[4] = 128; a.N[5] = 128;
        transpose6_k<<<dim3(8, 8, 6), 256, 0, stream>>>(a);
    }

    // ---- batched CSR build for all 4 graphs ----
    G4 a;
    a.g[0] = { eid_sim,  wd_sim,  Ed, Nd, (Nd + 255) >> 8, 0,           rp0, perm0 };
    a.g[1] = { eid_feat, wd_feat, Ed, Nd, (Nd + 255) >> 8, Ed,          rp1, perm1 };
    a.g[2] = { eis_sim,  ws_sim,  Es, Ns, (Ns + 255) >> 8, 2 * Ed,      rp2, perm2 };
    a.g[3] = { eis_feat, ws_feat, Es, Ns, (Ns + 255) >> 8, 2 * Ed + Es, rp3, perm3 };
    {
        const int maxEB = (Ed + 4095) / 4096;
        const int maxNB = (Nd + 255) >> 8;
        hipMemsetAsync(bcounts, 0, 4 * 512 * 4, stream);
        hist_b<<<dim3(maxEB, 4), 256, 0, stream>>>(a, bcounts);
        scan_b<<<4, 256, 0, stream>>>(a, bcounts, bbase, bcursor);
        scatter_b<<<dim3(maxEB, 4), 256, 0, stream>>>(a, bcursor, bst);
        finalize_b<<<dim3(maxNB, 4), 256, 0, stream>>>(a, bbase, bst);
    }

    // ---- per-branch compute ----
    auto branch = [&](const float* X, int n,
                      const int2* pA, const int* rpA,
                      const int2* pB, const int* rpB,
                      const ushort* W1t, const float* b1,
                      const ushort* W2t, const float* b2,
                      const ushort* Wft, const float* bfu,
                      float* o_sim, float* o_feat, float* o_emb) {
        gemm_mfma<true, false, false, false, false><<<dim3((n + 127) / 128, 2), 256, 0, stream>>>(
            X, nullptr, W1t, nullptr, xw1, nullptr, n, 256, 256);
        const int2* pm[2] = {pA, pB};
        const int*  rp[2] = {rpA, rpB};
        float*      of[2] = {o_sim, o_feat};
        ushort*     oh[2] = {es_h, ef_h};
        for (int g = 0; g < 2; ++g) {
            spmm_f16<4, true, false><<<(n + 3) / 4, 256, 0, stream>>>(
                (const f16*)xw1, pm[g], rp[g], b1, hbuf, nullptr, n);
            gemm_mfma<false, false, false, false, false><<<dim3((n + 127) / 128, 1), 256, 0, stream>>>(
                hbuf, nullptr, W2t, nullptr, tbuf, nullptr, n, 128, 256);
            spmm_f16<2, false, true><<<(n + 3) / 4, 256, 0, stream>>>(
                (const f16*)tbuf, pm[g], rp[g], b2, oh[g], of[g], n);
        }
        gemm_mfma<false, true, true, true, true><<<dim3((n + 127) / 128, 1), 256, 0, stream>>>(
            es_h, ef_h, Wft, bfu, nullptr, o_emb, n, 128, 256);
    };

    branch(Xd, Nd, perm0, rp0, perm1, rp1,
           W1dt, b1d, W2dt, b2d, Wfdt, bfd, o_e1s, o_e1f, o_emb1);
    branch(Xs, Ns, perm2, rp2, perm3, rp3,
           W1st, b1s, W2st, b2s, Wfst, bfs, o_e2s, o_e2f, o_emb2);
}

// Round 6
// 1379.248 us; speedup vs baseline: 3.6618x; 1.0038x over previous
//
#include <hip/hip_runtime.h>

typedef _Float16 f16;
typedef __attribute__((ext_vector_type(8))) _Float16 f16x8;
typedef __attribute__((ext_vector_type(4))) float f32x4;

__device__ inline ushort f2h_bits(float f) {
    f16 h = (f16)f;
    return __builtin_bit_cast(ushort, h);
}

// ---------------------------------------------------------------------------
// Batched weight transpose+convert: W[K,N] f32 -> Wt[N,K] f16, 6 weights.
// ---------------------------------------------------------------------------
struct T6 {
    const float* s[6];
    ushort* d[6];
    int N[6];
};

__global__ __launch_bounds__(256) void transpose6_k(T6 a) {
    __shared__ ushort tile[32][33];
    const int z = blockIdx.z;
    const int K = 256, N = a.N[z];
    int k0 = blockIdx.x * 32, n0 = blockIdx.y * 32;
    if (n0 >= N) return;
    const float* W = a.s[z];
    ushort* Wt = a.d[z];
    int tx = threadIdx.x & 31, ty = threadIdx.x >> 5;
    #pragma unroll
    for (int i = 0; i < 32; i += 8)
        tile[ty + i][tx] = f2h_bits(W[(size_t)(k0 + ty + i) * N + n0 + tx]);
    __syncthreads();
    #pragma unroll
    for (int i = 0; i < 32; i += 8)
        Wt[(size_t)(n0 + ty + i) * K + k0 + tx] = tile[tx][ty + i];
}

// ---------------------------------------------------------------------------
// Batched CSR build (4 graphs), two-level binned (buckets of 256 rows).
// ---------------------------------------------------------------------------
struct GraphDesc {
    const int* ei;      // [2,E]: dst = ei[0..E), src = ei[E..2E)
    const float* w;
    int E, n, NB, bstoff;
    int* row_ptr;       // [n+1]
    int2* perm;         // [E] (src, w_bits)
};
struct G4 { GraphDesc g[4]; };

__global__ __launch_bounds__(256) void hist_b(G4 a, int* __restrict__ bcounts) {
    const GraphDesc& G = a.g[blockIdx.y];
    const int e0 = blockIdx.x * 4096;
    if (e0 >= G.E) return;
    __shared__ int h[512];
    int t = threadIdx.x;
    h[t] = 0; h[t + 256] = 0;
    __syncthreads();
    #pragma unroll
    for (int k = 0; k < 16; ++k) {
        int i = e0 + t + k * 256;
        if (i < G.E) atomicAdd(&h[((uint)G.ei[i]) >> 8], 1);
    }
    __syncthreads();
    int* bc = bcounts + blockIdx.y * 512;
    for (int b = t; b < 512; b += 256)
        if (h[b]) atomicAdd(&bc[b], h[b]);
}

__global__ __launch_bounds__(256) void scan_b(G4 a, const int* __restrict__ bcounts,
                                              int* __restrict__ bbase, int* __restrict__ bcursor) {
    const int gidx = blockIdx.x;
    const GraphDesc& G = a.g[gidx];
    const int* bc = bcounts + gidx * 512;
    int* base = bbase + gidx * 513;
    int* cur  = bcursor + gidx * 512;
    int t = threadIdx.x, lane = t & 63, wave = t >> 6;
    int v0 = bc[2 * t], v1 = bc[2 * t + 1];
    int s = v0 + v1;
    int incl = s;
    for (int off = 1; off < 64; off <<= 1) {
        int u = __shfl_up(incl, off);
        if (lane >= off) incl += u;
    }
    __shared__ int wsum[4];
    if (lane == 63) wsum[wave] = incl;
    __syncthreads();
    int excl = incl - s;
    for (int wv = 0; wv < wave; ++wv) excl += wsum[wv];
    base[2 * t] = excl;      cur[2 * t] = excl;
    base[2 * t + 1] = excl + v0; cur[2 * t + 1] = excl + v0;
    if (t == 0) { base[512] = G.E; G.row_ptr[G.n] = G.E; }
}

__global__ __launch_bounds__(256) void scatter_b(G4 a, int* __restrict__ bcursor,
                                                 int2* __restrict__ bst) {
    const GraphDesc& G = a.g[blockIdx.y];
    const int e0 = blockIdx.x * 4096;
    if (e0 >= G.E) return;
    __shared__ int hist[512], excl[512], sbase[512], lcur[512];
    __shared__ int2 stage[4096];
    __shared__ ushort sbin[4096];
    const int t = threadIdx.x, lane = t & 63, wave = t >> 6;
    const int cnt = min(4096, G.E - e0);
    int* bcur = bcursor + blockIdx.y * 512;

    hist[t] = 0; hist[t + 256] = 0;
    __syncthreads();

    int   d[16], s[16];
    float wv[16];
    #pragma unroll
    for (int k = 0; k < 16; ++k) {
        int i = t + k * 256;
        if (i < cnt) {
            d[k]  = G.ei[e0 + i];
            s[k]  = G.ei[(size_t)G.E + e0 + i];
            wv[k] = G.w[e0 + i];
            atomicAdd(&hist[((uint)d[k]) >> 8], 1);
        }
    }
    __syncthreads();

    {
        int v0 = hist[2 * t], v1 = hist[2 * t + 1];
        int sum = v0 + v1;
        int incl = sum;
        for (int off = 1; off < 64; off <<= 1) {
            int u = __shfl_up(incl, off);
            if (lane >= off) incl += u;
        }
        __shared__ int wsum[4];
        if (lane == 63) wsum[wave] = incl;
        __syncthreads();
        int e = incl - sum;
        for (int wvv = 0; wvv < wave; ++wvv) e += wsum[wvv];
        excl[2 * t] = e; excl[2 * t + 1] = e + v0;
    }
    __syncthreads();

    for (int b = t; b < 512; b += 256) {
        int c = hist[b];
        sbase[b] = c ? atomicAdd(&bcur[b], c) : 0;
        lcur[b] = excl[b];
    }
    __syncthreads();

    #pragma unroll
    for (int k = 0; k < 16; ++k) {
        int i = t + k * 256;
        if (i < cnt) {
            int bin = ((uint)d[k]) >> 8;
            int pos = atomicAdd(&lcur[bin], 1);
            stage[pos] = make_int2((s[k] << 8) | (d[k] & 255), __float_as_int(wv[k]));
            sbin[pos] = (ushort)bin;
        }
    }
    __syncthreads();

    #pragma unroll
    for (int k = 0; k < 16; ++k) {
        int i = t + k * 256;
        if (i < cnt) {
            int2 r = stage[i];
            int bin = sbin[i];
            bst[(size_t)G.bstoff + sbase[bin] + i - excl[bin]] = r;
        }
    }
}

__global__ __launch_bounds__(256) void finalize_b(G4 a, const int* __restrict__ bbase,
                                                  const int2* __restrict__ bst) {
    const GraphDesc& G = a.g[blockIdx.y];
    const int b = blockIdx.x;
    if (b >= G.NB) return;
    __shared__ int hist[256], cur[256], wsum[4];
    const int t = threadIdx.x, lane = t & 63, wave = t >> 6;
    const int* base = bbase + blockIdx.y * 513;
    const int lo = base[b], hi = base[b + 1];
    const int2* bg = bst + G.bstoff;
    hist[t] = 0;
    __syncthreads();
    for (int i = lo + t; i < hi; i += 256)
        atomicAdd(&hist[bg[i].x & 255], 1);
    __syncthreads();
    int v = hist[t];
    int incl = v;
    for (int off = 1; off < 64; off <<= 1) {
        int u = __shfl_up(incl, off);
        if (lane >= off) incl += u;
    }
    if (lane == 63) wsum[wave] = incl;
    __syncthreads();
    int excl = incl - v;
    for (int wv = 0; wv < wave; ++wv) excl += wsum[wv];
    const int r0 = b << 8;
    const int nrows = min(256, G.n - r0);
    if (t < nrows) G.row_ptr[r0 + t] = lo + excl;
    cur[t] = lo + excl;
    __syncthreads();
    for (int i = lo + t; i < hi; i += 256) {
        int2 r = bg[i];
        int local = r.x & 255;
        int slot = atomicAdd(&cur[local], 1);
        G.perm[slot] = make_int2(r.x >> 8, r.y);
    }
}

// ---------------------------------------------------------------------------
// Paired L1 SpMM: two edge sets gathering from the SAME table (better L2
// temporal reuse). blockIdx.y selects graph. out = relu(spmm + bias), f16.
// ---------------------------------------------------------------------------
struct PairDesc {
    const int2* perm[2];
    const int*  rp[2];
    ushort*     outh[2];
};

template<int C>
__global__ __launch_bounds__(256) void spmm_pair_f16(
    const f16* __restrict__ x, PairDesc a, const float* __restrict__ bias, int n)
{
    const int g = blockIdx.y;
    const int wave = threadIdx.x >> 6, lane = threadIdx.x & 63;
    const int row = blockIdx.x * 4 + wave;
    if (row >= n) return;
    const int2* __restrict__ perm = a.perm[g];
    const int*  __restrict__ rp   = a.rp[g];
    const int F = 64 * C;
    const int e0 = rp[row], e1 = rp[row + 1];
    float acc[C] = {};
    const int laneoff = lane * C;

    for (int eb = e0; eb < e1; eb += 64) {
        int idx = eb + lane;
        int myS = 0; int myW = 0;
        if (idx < e1) { int2 rec = perm[idx]; myS = rec.x; myW = rec.y; }
        int m = min(64, e1 - eb);
        for (int j0 = 0; j0 < m; j0 += 8) {
            #pragma unroll
            for (int u = 0; u < 8; ++u) {
                int j = j0 + u;   // padded lanes carry w=0
                int   s = __builtin_amdgcn_readlane(myS, j);
                float w = __int_as_float(__builtin_amdgcn_readlane(myW, j));
                const f16* xr = x + (size_t)((uint)s * (uint)F) + laneoff;
                union { uint2 u2; f16 h[4]; } cv;
                cv.u2 = *reinterpret_cast<const uint2*>(xr);
                acc[0] = fmaf((float)cv.h[0], w, acc[0]);
                acc[1] = fmaf((float)cv.h[1], w, acc[1]);
                acc[2] = fmaf((float)cv.h[2], w, acc[2]);
                acc[3] = fmaf((float)cv.h[3], w, acc[3]);
            }
        }
    }

    #pragma unroll
    for (int c = 0; c < C; ++c) {
        float v = acc[c] + bias[laneoff + c];
        acc[c] = fmaxf(v, 0.f);
    }
    *reinterpret_cast<ushort4*>(a.outh[g] + (size_t)row * F + laneoff) =
        make_ushort4(f2h_bits(acc[0]), f2h_bits(acc[1]), f2h_bits(acc[2]), f2h_bits(acc[3]));
}

// ---------------------------------------------------------------------------
// L2 SpMM (single graph): out = spmm + bias -> f16 + f32 outputs. F = 128.
// ---------------------------------------------------------------------------
__global__ __launch_bounds__(256) void spmm_l2_f16(
    const f16* __restrict__ x,
    const int2* __restrict__ perm,
    const int* __restrict__ row_ptr, const float* __restrict__ bias,
    ushort* __restrict__ out_h, float* __restrict__ out_f, int n)
{
    const int wave = threadIdx.x >> 6, lane = threadIdx.x & 63;
    const int row = blockIdx.x * 4 + wave;
    if (row >= n) return;
    const int F = 128;
    const int e0 = row_ptr[row], e1 = row_ptr[row + 1];
    float acc[2] = {};
    const int laneoff = lane * 2;

    for (int eb = e0; eb < e1; eb += 64) {
        int idx = eb + lane;
        int myS = 0; int myW = 0;
        if (idx < e1) { int2 rec = perm[idx]; myS = rec.x; myW = rec.y; }
        int m = min(64, e1 - eb);
        for (int j0 = 0; j0 < m; j0 += 8) {
            #pragma unroll
            for (int u = 0; u < 8; ++u) {
                int j = j0 + u;
                int   s = __builtin_amdgcn_readlane(myS, j);
                float w = __int_as_float(__builtin_amdgcn_readlane(myW, j));
                union { uint u1; f16 h[2]; } cv;
                cv.u1 = *reinterpret_cast<const uint*>(x + (size_t)((uint)s * (uint)F) + laneoff);
                acc[0] = fmaf((float)cv.h[0], w, acc[0]);
                acc[1] = fmaf((float)cv.h[1], w, acc[1]);
            }
        }
    }

    acc[0] += bias[laneoff];
    acc[1] += bias[laneoff + 1];
    size_t ob = (size_t)row * F + laneoff;
    *reinterpret_cast<float2*>(out_f + ob) = make_float2(acc[0], acc[1]);
    *reinterpret_cast<ushort2*>(out_h + ob) = make_ushort2(f2h_bits(acc[0]), f2h_bits(acc[1]));
}

// ---------------------------------------------------------------------------
// f16 MFMA GEMM: C[M,N] = A[M,K] @ Bt[N,K]^T, 128x128 tile, BK=32, 4 waves.
// SWAP: bn from blockIdx.x (N fastest -> A-tile reuse across N-blocks).
// CVTA: A is f32, converted inline. FUSE: A = concat([A,A2]), each [M,128].
// ---------------------------------------------------------------------------
template<bool SWAP, bool CVTA, bool FUSE, bool RELU, bool BIAS, bool F32OUT>
__global__ __launch_bounds__(256) void gemm_mfma(
    const void* __restrict__ Av, const ushort* __restrict__ A2,
    const ushort* __restrict__ Bt, const float* __restrict__ bias,
    ushort* __restrict__ Ch, float* __restrict__ Cf,
    int M, int N, int K)
{
    __shared__ ushort Asb[128 * 32];
    __shared__ ushort Bsb[128 * 32];
    const int tid = threadIdx.x;
    const int lane = tid & 63, wave = tid >> 6;
    const int wr = wave >> 1, wc = wave & 1;
    const int bm = (SWAP ? blockIdx.y : blockIdx.x) * 128;
    const int bn = (SWAP ? blockIdx.x : blockIdx.y) * 128;

    f32x4 acc[4][4] = {};

    for (int k0 = 0; k0 < K; k0 += 32) {
        #pragma unroll
        for (int h = 0; h < 2; ++h) {
            int slot = tid + 256 * h;
            int r = slot >> 2, cb = slot & 3;
            int row = bm + r;
            uint4 v = make_uint4(0, 0, 0, 0);
            if (row < M) {
                int kk = k0 + cb * 8;
                if (CVTA) {
                    const float* Af = (const float*)Av;
                    float4 lo = *reinterpret_cast<const float4*>(Af + (size_t)row * K + kk);
                    float4 hi = *reinterpret_cast<const float4*>(Af + (size_t)row * K + kk + 4);
                    ushort h8[8] = { f2h_bits(lo.x), f2h_bits(lo.y), f2h_bits(lo.z), f2h_bits(lo.w),
                                     f2h_bits(hi.x), f2h_bits(hi.y), f2h_bits(hi.z), f2h_bits(hi.w) };
                    v = *reinterpret_cast<const uint4*>(h8);
                } else if (FUSE) {
                    const ushort* Ap = (kk < 128) ? (const ushort*)Av : A2;
                    v = *reinterpret_cast<const uint4*>(Ap + (size_t)row * 128 + (kk & 127));
                } else {
                    v = *reinterpret_cast<const uint4*>((const ushort*)Av + (size_t)row * K + kk);
                }
            }
            int scb = cb ^ ((r >> 1) & 3);
            *reinterpret_cast<uint4*>(&Asb[r * 32 + scb * 8]) = v;
        }
        #pragma unroll
        for (int h = 0; h < 2; ++h) {
            int slot = tid + 256 * h;
            int r = slot >> 2, cb = slot & 3;
            uint4 v = *reinterpret_cast<const uint4*>(Bt + (size_t)(bn + r) * K + k0 + cb * 8);
            int scb = cb ^ ((r >> 1) & 3);
            *reinterpret_cast<uint4*>(&Bsb[r * 32 + scb * 8]) = v;
        }
        __syncthreads();

        f16x8 fa[4], fb[4];
        #pragma unroll
        for (int i = 0; i < 4; ++i) {
            int r = wr * 64 + i * 16 + (lane & 15);
            int scb = (lane >> 4) ^ ((r >> 1) & 3);
            fa[i] = *reinterpret_cast<const f16x8*>(&Asb[r * 32 + scb * 8]);
        }
        #pragma unroll
        for (int j = 0; j < 4; ++j) {
            int r = wc * 64 + j * 16 + (lane & 15);
            int scb = (lane >> 4) ^ ((r >> 1) & 3);
            fb[j] = *reinterpret_cast<const f16x8*>(&Bsb[r * 32 + scb * 8]);
        }
        #pragma unroll
        for (int i = 0; i < 4; ++i)
            #pragma unroll
            for (int j = 0; j < 4; ++j)
                acc[i][j] = __builtin_amdgcn_mfma_f32_16x16x32_f16(fa[i], fb[j], acc[i][j], 0, 0, 0);
        __syncthreads();
    }

    #pragma unroll
    for (int i = 0; i < 4; ++i) {
        #pragma unroll
        for (int r4 = 0; r4 < 4; ++r4) {
            int row = bm + wr * 64 + i * 16 + (lane >> 4) * 4 + r4;
            if (row >= M) continue;
            #pragma unroll
            for (int j = 0; j < 4; ++j) {
                int col = bn + wc * 64 + j * 16 + (lane & 15);
                float v = acc[i][j][r4];
                if (BIAS) v += bias[col];
                if (RELU) v = fmaxf(v, 0.f);
                if (F32OUT) Cf[(size_t)row * N + col] = v;
                else        Ch[(size_t)row * N + col] = f2h_bits(v);
            }
        }
    }
}

// ---------------------------------------------------------------------------
// Orchestration
// ---------------------------------------------------------------------------
extern "C" void kernel_launch(void* const* d_in, const int* in_sizes, int n_in,
                              void* d_out, int out_size, void* d_ws, size_t ws_size,
                              hipStream_t stream) {
    const float* Xd       = (const float*)d_in[0];
    const int*   eid_sim  = (const int*)  d_in[1];
    const float* wd_sim   = (const float*)d_in[2];
    const int*   eid_feat = (const int*)  d_in[3];
    const float* wd_feat  = (const float*)d_in[4];
    const float* Xs       = (const float*)d_in[5];
    const int*   eis_sim  = (const int*)  d_in[6];
    const float* ws_sim   = (const float*)d_in[7];
    const int*   eis_feat = (const int*)  d_in[8];
    const float* ws_feat  = (const float*)d_in[9];
    const float* W1d = (const float*)d_in[10]; const float* b1d = (const float*)d_in[11];
    const float* W2d = (const float*)d_in[12]; const float* b2d = (const float*)d_in[13];
    const float* W1s = (const float*)d_in[14]; const float* b1s = (const float*)d_in[15];
    const float* W2s = (const float*)d_in[16]; const float* b2s = (const float*)d_in[17];
    const float* Wfd = (const float*)d_in[18]; const float* bfd = (const float*)d_in[19];
    const float* Wfs = (const float*)d_in[20]; const float* bfs = (const float*)d_in[21];

    const int Fd = 256, H1 = 256, H2 = 128;
    const int Nd = in_sizes[0] / Fd;
    const int Ns = in_sizes[5] / Fd;
    const int Ed = in_sizes[2];
    const int Es = in_sizes[7];

    float* out    = (float*)d_out;
    float* o_emb1 = out;
    float* o_emb2 = o_emb1 + (size_t)Nd * H2;
    float* o_e1s  = o_emb2 + (size_t)Ns * H2;
    float* o_e1f  = o_e1s  + (size_t)Nd * H2;
    float* o_e2s  = o_e1f  + (size_t)Nd * H2;
    float* o_e2f  = o_e2s  + (size_t)Ns * H2;

    char* p = (char*)d_ws;
    auto alloc = [&](size_t bytes) { char* q = p; p += (bytes + 255) & ~(size_t)255; return q; };
    ushort* xw1   = (ushort*)alloc((size_t)Nd * 256 * 2);
    ushort* hbuf0 = (ushort*)alloc((size_t)Nd * 256 * 2);
    ushort* hbuf1 = (ushort*)alloc((size_t)Nd * 256 * 2);
    ushort* tbuf0 = (ushort*)alloc((size_t)Nd * 128 * 2);
    ushort* tbuf1 = (ushort*)alloc((size_t)Nd * 128 * 2);
    ushort* W1dt  = (ushort*)alloc(256 * 256 * 2);
    ushort* W2dt  = (ushort*)alloc(256 * 128 * 2);
    ushort* Wfdt  = (ushort*)alloc(256 * 128 * 2);
    ushort* W1st  = (ushort*)alloc(256 * 256 * 2);
    ushort* W2st  = (ushort*)alloc(256 * 128 * 2);
    ushort* Wfst  = (ushort*)alloc(256 * 128 * 2);
    int2*   perm0 = (int2*)alloc((size_t)Ed * 8);
    int2*   perm1 = (int2*)alloc((size_t)Ed * 8);
    int2*   perm2 = (int2*)alloc((size_t)Es * 8);
    int2*   perm3 = (int2*)alloc((size_t)Es * 8);
    int*    rp0   = (int*) alloc((size_t)(Nd + 1) * 4);
    int*    rp1   = (int*) alloc((size_t)(Nd + 1) * 4);
    int*    rp2   = (int*) alloc((size_t)(Ns + 1) * 4);
    int*    rp3   = (int*) alloc((size_t)(Ns + 1) * 4);
    int*    bcounts = (int*)alloc(4 * 512 * 4);
    int*    bbase   = (int*)alloc(4 * 513 * 4);
    int*    bcursor = (int*)alloc(4 * 512 * 4);
    // aliases: bst over hbuf0+hbuf1 (dead during CSR build; 2(Ed+Es)*8 <= 2*Nd*512B)
    int2*   bst  = (int2*)hbuf0;
    // es/ef over xw1 (xw1 dead after the branch's L1 spmm pair)
    ushort* es_h = xw1;
    ushort* ef_h = xw1 + (size_t)Nd * 128;

    // ---- batched weight transposes ----
    {
        T6 a;
        a.s[0] = W1d; a.s[1] = W2d; a.s[2] = Wfd; a.s[3] = W1s; a.s[4] = W2s; a.s[5] = Wfs;
        a.d[0] = W1dt; a.d[1] = W2dt; a.d[2] = Wfdt; a.d[3] = W1st; a.d[4] = W2st; a.d[5] = Wfst;
        a.N[0] = 256; a.N[1] = 128; a.N[2] = 128; a.N[3] = 256; a.N[4] = 128; a.N[5] = 128;
        transpose6_k<<<dim3(8, 8, 6), 256, 0, stream>>>(a);
    }

    // ---- batched CSR build for all 4 graphs (runs before hbuf is live) ----
    G4 a;
    a.g[0] = { eid_sim,  wd_sim,  Ed, Nd, (Nd + 255) >> 8, 0,           rp0, perm0 };
    a.g[1] = { eid_feat, wd_feat, Ed, Nd, (Nd + 255) >> 8, Ed,          rp1, perm1 };
    a.g[2] = { eis_sim,  ws_sim,  Es, Ns, (Ns + 255) >> 8, 2 * Ed,      rp2, perm2 };
    a.g[3] = { eis_feat, ws_feat, Es, Ns, (Ns + 255) >> 8, 2 * Ed + Es, rp3, perm3 };
    {
        const int maxEB = (Ed + 4095) / 4096;
        const int maxNB = (Nd + 255) >> 8;
        hipMemsetAsync(bcounts, 0, 4 * 512 * 4, stream);
        hist_b<<<dim3(maxEB, 4), 256, 0, stream>>>(a, bcounts);
        scan_b<<<4, 256, 0, stream>>>(a, bcounts, bbase, bcursor);
        scatter_b<<<dim3(maxEB, 4), 256, 0, stream>>>(a, bcursor, bst);
        finalize_b<<<dim3(maxNB, 4), 256, 0, stream>>>(a, bbase, bst);
    }

    // ---- per-branch compute ----
    auto branch = [&](const float* X, int n,
                      const int2* pA, const int* rpA,
                      const int2* pB, const int* rpB,
                      const ushort* W1t, const float* b1,
                      const ushort* W2t, const float* b2,
                      const ushort* Wft, const float* bfu,
                      float* o_sim, float* o_feat, float* o_emb) {
        const int Mb = (n + 127) / 128;
        // xw1 = f16(X) @ W1 ; N-fastest grid so the A f32 tile is read once hot
        gemm_mfma<true, true, false, false, false, false><<<dim3(2, Mb), 256, 0, stream>>>(
            X, nullptr, W1t, nullptr, xw1, nullptr, n, 256, 256);
        // both graphs gather from the same xw1 table in one dispatch
        PairDesc pd;
        pd.perm[0] = pA; pd.perm[1] = pB;
        pd.rp[0] = rpA;  pd.rp[1] = rpB;
        pd.outh[0] = hbuf0; pd.outh[1] = hbuf1;
        spmm_pair_f16<4><<<dim3((n + 3) / 4, 2), 256, 0, stream>>>(
            (const f16*)xw1, pd, b1, n);
        // t_g = h_g @ W2 ; then L2 spmm per graph (separate tables)
        gemm_mfma<false, false, false, false, false, false><<<dim3(Mb, 1), 256, 0, stream>>>(
            hbuf0, nullptr, W2t, nullptr, tbuf0, nullptr, n, 128, 256);
        gemm_mfma<false, false, false, false, false, false><<<dim3(Mb, 1), 256, 0, stream>>>(
            hbuf1, nullptr, W2t, nullptr, tbuf1, nullptr, n, 128, 256);
        spmm_l2_f16<<<(n + 3) / 4, 256, 0, stream>>>(
            (const f16*)tbuf0, pA, rpA, b2, es_h, o_sim, n);
        spmm_l2_f16<<<(n + 3) / 4, 256, 0, stream>>>(
            (const f16*)tbuf1, pB, rpB, b2, ef_h, o_feat, n);
        // fusion: relu(concat(es,ef) @ Wf + bf)
        gemm_mfma<false, false, true, true, true, true><<<dim3(Mb, 1), 256, 0, stream>>>(
            es_h, ef_h, Wft, bfu, nullptr, o_emb, n, 128, 256);
    };

    branch(Xd, Nd, perm0, rp0, perm1, rp1,
           W1dt, b1d, W2dt, b2d, Wfdt, bfd, o_e1s, o_e1f, o_emb1);
    branch(Xs, Ns, perm2, rp2, perm3, rp3,
           W1st, b1s, W2st, b2s, Wfst, bfs, o_e2s, o_e2f, o_emb2);
}